// Round 10
// baseline (376.436 us; speedup 1.0000x reference)
//
#include <hip/hip_runtime.h>
#include <hip/hip_bf16.h>

#define TD 49
#define BD 16
#define ND 64
#define HD 128

typedef float  f32x4  __attribute__((ext_vector_type(4)));
typedef __bf16 bf16x8 __attribute__((ext_vector_type(8)));
typedef __bf16 bf16x4 __attribute__((ext_vector_type(4)));

// ---------------- workspace layout (bf16 element offsets) ----------------
// W' [t*8+g][h=128][k=640], k-order = [U | Wt0 | Wt1 | Wt2 | Ws]
#define WP_OFF   0u
#define HB_OFF   32112640u           // h  bf16 [B,T,N,H]
#define ACT_ELEMS 6422528u
#define PB_OFF   38535168u           // p  bf16
#define GB_OFF   44957696u           // g_t bf16 [B,T,H]
#define GT_ELEMS 100352u
#define ZP_OFF   45058048u           // 2048 bf16 zeros (pad source page)
#define ZB_OFF   45060096u           // f32 zb[b,t,g,h] = Zt.g_t + b  (802816 f32)

#define OUT_H    0
#define OUT_CH   6422528
#define OUT_G    12845056
#define OUT_CG   12945408

#define KPAD 136
#define LDS1_BYTES 65536             // 4 slots x (A 8KB + B 8KB) -> 2 blocks/CU
#define LDS2_BYTES 118784

#define NB_ACTS 12644
#define NB_ZB   392                  // 49*8

__device__ __forceinline__ float sigf(float x) {
    return 1.0f / (1.0f + exp2f(-1.442695041f * x));
}
__device__ __forceinline__ float tanhf_fast(float x) {
    x = fminf(fmaxf(x, -20.f), 20.f);
    float e = exp2f(2.885390082f * x);
    return (e - 1.f) / (e + 1.f);
}
__device__ __forceinline__ void gload16(const void* g, void* l) {
    __builtin_amdgcn_global_load_lds((const __attribute__((address_space(1))) void*)g,
                                     (__attribute__((address_space(3))) void*)l, 16, 0, 0);
}

// ---------------------------------------------------------------------------
// prep_actszb: [0,NB_ACTS) streaming cast h/p/g_t -> bf16 + zero page;
//              [NB_ACTS, +NB_ZB) zb[b,t,g,h] = sum_k g_t*Zt + bias (f32).
// No LDS anywhere.
// ---------------------------------------------------------------------------
__global__ __launch_bounds__(256) void prep_actszb(
    const float* __restrict__ h, const float* __restrict__ p,
    const float* __restrict__ g, const float* __restrict__ Zt,
    const float* __restrict__ bias, __bf16* __restrict__ ws)
{
    const int bid = blockIdx.x;
    const int tid = threadIdx.x;

    if (bid < NB_ACTS) {
        unsigned i = bid * 256u + tid;
        const unsigned HU = ACT_ELEMS / 4u, GU = GT_ELEMS / 4u;
        const float* src;
        unsigned dst;
        if (i < HU)              { src = h + (size_t)i * 4;            dst = HB_OFF + i * 4; }
        else if (i < 2u*HU)      { unsigned j = i - HU;    src = p + (size_t)j * 4; dst = PB_OFF + j * 4; }
        else if (i < 2u*HU + GU) { unsigned j = i - 2u*HU; src = g + (size_t)j * 4; dst = GB_OFF + j * 4; }
        else if (i < 2u*HU + GU + 512u) {
            unsigned j = i - 2u*HU - GU;
            bf16x4 z = {};
            *(bf16x4*)(ws + ZP_OFF + j * 4) = z;
            return;
        } else return;
        f32x4 v = *(const f32x4*)src;
        bf16x4 w;
        w[0] = (__bf16)v[0]; w[1] = (__bf16)v[1]; w[2] = (__bf16)v[2]; w[3] = (__bf16)v[3];
        *(bf16x4*)(ws + dst) = w;
        return;
    }

    // ---- zb: block = (t, gate)
    {
        int zid = bid - NB_ACTS;
        int t = zid >> 3, gg = zid & 7;
        int h_ = tid & 127, bh = tid >> 7;          // 2 halves x 8 batches
        float* zbf = (float*)(ws + ZB_OFF);
        float s[8];
        float bv = bias[(gg * TD + t) * HD + h_];
#pragma unroll
        for (int b8 = 0; b8 < 8; ++b8) s[b8] = bv;
        const float* Zrow = Zt + ((size_t)(gg * TD + t) << 14) + h_;
        for (int k = 0; k < 128; ++k) {
            float zv = Zrow[k << 7];
#pragma unroll
            for (int b8 = 0; b8 < 8; ++b8)
                s[b8] += g[(((bh * 8 + b8) * TD + t) << 7) + k] * zv;
        }
#pragma unroll
        for (int b8 = 0; b8 < 8; ++b8) {
            int bt = (bh * 8 + b8) * TD + t;
            zbf[(bt * 8 + gg) * HD + h_] = s[b8];
        }
    }
}

// ---------------------------------------------------------------------------
// prep_w v2: register transpose, no LDS. Block = (tg, kc 128-k chunk); lane
// unit = one h-row x 8 k's: 8 strided f32 loads -> bf16x8 coalesced write.
// grid = 392 * 5.
// ---------------------------------------------------------------------------
__global__ __launch_bounds__(256) void prep_w(
    const float* __restrict__ U, const float* __restrict__ Wt,
    const float* __restrict__ Ws, __bf16* __restrict__ wp)
{
    int bid = blockIdx.x;
    int tg = bid / 5, kc = bid % 5;
    int t = tg >> 3, gg = tg & 7;
    int gt = gg * TD + t;
    const float* S;
    int kloc0;
    if (kc == 0)      { S = U  + ((size_t)gt << 14); kloc0 = 0; }
    else if (kc <= 3) { S = Wt + (size_t)gt * 49152; kloc0 = (kc - 1) * 128; }
    else              { S = Ws + ((size_t)gt << 14); kloc0 = 0; }
    int tid = threadIdx.x;
    __bf16* wrow = wp + (size_t)tg * 81920 + kc * 128;
#pragma unroll
    for (int u = 0; u < 8; ++u) {
        int gid = u * 256 + tid;              // [0,2048)
        int hh = gid >> 4, kq = gid & 15;
        const float* s = S + (size_t)(kloc0 + kq * 8) * 128 + hh;
        bf16x8 w;
#pragma unroll
        for (int j = 0; j < 8; ++j) w[j] = (__bf16)s[j * 128];
        *(bf16x8*)(wrow + (size_t)hh * 640 + kq * 8) = w;
    }
}

// ---------------------------------------------------------------------------
// Phase 1: 128x128 tile (M=128, N = 8 gates x 16 hcols), BK=32, K=640
// (20 steps), 4 LDS slots, depth-3 prefetch, counted vmcnt(8) + raw barrier.
// 4 waves, wave = 32 rows x all 8 gates (in-register gate epilogue, bias=zb).
// ---------------------------------------------------------------------------
__global__ __launch_bounds__(256, 2) void phase1_kernel(
    const __bf16* __restrict__ ws,
    const float* __restrict__ c_h, const float* __restrict__ c_g_t,
    float* __restrict__ out)
{
    extern __shared__ __bf16 smem[];     // A slots elems [0,16384); B: [16384,32768)
    const __bf16* hb = ws + HB_OFF;
    const __bf16* pb = ws + PB_OFF;
    const __bf16* wp = ws + WP_OFF;
    const __bf16* zp = ws + ZP_OFF;
    const float*  zb = (const float*)(ws + ZB_OFF);

    int bid = blockIdx.x;
    int swz = (bid & 7) * 392 + (bid >> 3);  // bijective, 3136 = 8*392
    int t     = swz >> 6;
    int rem   = swz & 63;
    int mtile = rem >> 3, ntile = rem & 7;

    int tid  = threadIdx.x;
    int wave = tid >> 6, lane = tid & 63;
    int lg = lane >> 4, l16 = lane & 15;

    // ---- staging maps: chunk = it*256+tid covers 16B of a slot
    const __bf16* pA[2][5];
    const __bf16* pB[2];
    int dstA[2], dstB[2];
#pragma unroll
    for (int it = 0; it < 2; ++it) {
        int chunk = it * 256 + tid;          // [0,512)
        int row   = chunk >> 2;              // [0,128)
        int k16   = chunk & 3;
        int ke    = (k16 ^ ((row >> 1) & 3)) * 8;   // swizzled k elem offset
        int b_ = mtile * 2 + (row >> 6), n_ = row & 63, bt_ = b_ * TD + t;
        pA[it][0] = pb + ((bt_ * ND + n_) << 7) + ke;
        pA[it][1] = (t > 0)      ? hb + (((bt_ - 1) * ND + n_) << 7) + ke : zp + ke;
        pA[it][2] = hb + ((bt_ * ND + n_) << 7) + ke;
        pA[it][3] = (t < TD - 1) ? hb + (((bt_ + 1) * ND + n_) << 7) + ke : zp + ke;
        pA[it][4] = (n_ > 0)     ? hb + ((bt_ * ND + n_ - 1) << 7) + ke : zp + ke;
        int g_ = row >> 4, hc = row & 15;
        pB[it] = wp + (size_t)((t * 8 + g_) * 128 + ntile * 16 + hc) * 640 + ke;
        dstA[it] = chunk * 8;
        dstB[it] = 16384 + chunk * 8;
    }

    // ---- fragment read byte-offsets (A within slot; B folded +32768 bytes)
    int rbA[2], rbB[8];
#pragma unroll
    for (int mi = 0; mi < 2; ++mi) {
        int row = wave * 32 + mi * 16 + l16;
        rbA[mi] = row * 64 + ((lg ^ ((row >> 1) & 3)) << 4);
    }
#pragma unroll
    for (int g = 0; g < 8; ++g) {
        int row = g * 16 + l16;
        rbB[g] = 32768 + row * 64 + ((lg ^ ((row >> 1) & 3)) << 4);
    }

    f32x4 acc[2][8];
    const f32x4 vzero = {0.f, 0.f, 0.f, 0.f};
#pragma unroll
    for (int mi = 0; mi < 2; ++mi)
#pragma unroll
        for (int g = 0; g < 8; ++g) acc[mi][g] = vzero;

#define STAGE(KS) do {                                                          \
        _Pragma("unroll")                                                       \
        for (int it = 0; it < 2; ++it) {                                        \
            gload16(pA[it][(KS) >> 2] + ((KS) & 3) * 32,                        \
                    smem + ((KS) & 3) * 4096 + dstA[it]);                       \
            gload16(pB[it] + (KS) * 32,                                         \
                    smem + ((KS) & 3) * 4096 + dstB[it]);                       \
        }                                                                       \
    } while (0)

    STAGE(0); STAGE(1); STAGE(2);
    asm volatile("s_waitcnt vmcnt(8)" ::: "memory");   // tile 0 landed (1,2 in flight)
    __builtin_amdgcn_s_barrier();

#pragma unroll
    for (int ks = 0; ks < 20; ++ks) {
        if (ks + 3 < 20) STAGE(ks + 3);
        const char* base = (const char*)smem + (ks & 3) * 8192;
        bf16x8 af[2], bfr[8];
        af[0] = *(const bf16x8*)(base + rbA[0]);
        af[1] = *(const bf16x8*)(base + rbA[1]);
#pragma unroll
        for (int g = 0; g < 8; ++g)
            bfr[g] = *(const bf16x8*)(base + rbB[g]);
#pragma unroll
        for (int g = 0; g < 8; ++g) {
            acc[0][g] = __builtin_amdgcn_mfma_f32_16x16x32_bf16(af[0], bfr[g], acc[0][g], 0, 0, 0);
            acc[1][g] = __builtin_amdgcn_mfma_f32_16x16x32_bf16(af[1], bfr[g], acc[1][g], 0, 0, 0);
        }
        if (ks < 19) {
            if (ks < 17)       asm volatile("s_waitcnt vmcnt(8)" ::: "memory");
            else if (ks == 17) asm volatile("s_waitcnt vmcnt(4)" ::: "memory");
            else               asm volatile("s_waitcnt vmcnt(0)" ::: "memory");
            __builtin_amdgcn_s_barrier();
        }
    }
#undef STAGE

    // ---- epilogue: gates + cell update; bias comes from precomputed zb ----
    const int hcol = ntile * 16 + l16;
#pragma unroll
    for (int mi = 0; mi < 2; ++mi) {
#pragma unroll
        for (int r = 0; r < 4; ++r) {
            int RG = mtile * 128 + wave * 32 + mi * 16 + lg * 4 + r;
            int b  = RG >> 6, nn = RG & 63;
            int bt = b * TD + t;
            int base = ((bt * ND + nn) << 7) + hcol;
            const float* zrow = zb + (bt * 8) * HD + hcol;
            float pre[8];
#pragma unroll
            for (int g = 0; g < 8; ++g) pre[g] = acc[mi][g][r] + zrow[g * HD];
            float i_  = sigf(pre[0]);
            float flt = sigf(pre[1]);
            float fft = sigf(pre[2]);
            float frt = sigf(pre[3]);
            float fs  = sigf(pre[4]);
            float gn  = sigf(pre[5]);
            float on  = sigf(pre[6]);
            float cn  = tanhf_fast(pre[7]);
            float ccur = c_h[base];
            float ctb  = (t > 0)      ? c_h[base - ND * HD] : 0.f;
            float cta  = (t < TD - 1) ? c_h[base + ND * HD] : 0.f;
            float csb  = (nn > 0)     ? c_h[base - HD]      : 0.f;
            float cg   = c_g_t[(bt << 7) + hcol];
            float cnew = i_ * cn + flt * ctb + fft * ccur + frt * cta + fs * csb + gn * cg;
            float hnew = on * tanhf_fast(cnew);
            out[OUT_H  + base] = hnew;
            out[OUT_CH + base] = cnew;
        }
    }
}

// ---------------------------------------------------------------------------
// Phase 2: grid 49 t x 4 bq; block = 4 b's (1 wave each). Stages the six
// 128x128 matrices ONCE per block. hm from staged h_new; f_gtf via MFMA.
// ---------------------------------------------------------------------------
__global__ __launch_bounds__(256, 1) void phase2_kernel(
    const float* __restrict__ g_t, const float* __restrict__ c_g_t,
    const float* __restrict__ Wg,  const float* __restrict__ Zg,
    const float* __restrict__ bg,  float* __restrict__ out)
{
    extern __shared__ char sm2[];
    __bf16* A2  = (__bf16*)sm2;                       // [256][136] h_new bf16
    __bf16* Wb  = (__bf16*)(sm2 + 69632);             // [128][136] staging
    float*  gts = (float*)(sm2 + 69632 + 34816);      // [4][128]
    float*  hm  = (float*)(sm2 + 69632 + 34816 + 2048);
    float*  dts = (float*)(sm2 + 69632 + 34816 + 4096); // [5][4][128]

    int bid = blockIdx.x;
    int t = bid >> 2, bq = bid & 3;
    int tid = threadIdx.x;
    int wv = tid >> 6, lane = tid & 63, lg = lane >> 4, l16 = lane & 15;

    const float* hn  = out + OUT_H;
    const float* chn = out + OUT_CH;

#pragma unroll
    for (int j = 0; j < 32; ++j) {
        int fid = j * 256 + tid;
        int r = fid >> 5, k = (fid & 31) << 2;
        int b = bq * 4 + (r >> 6), nn = r & 63, bt = b * TD + t;
        f32x4 v = *(const f32x4*)(hn + ((bt * ND + nn) << 7) + k);
        bf16x4 w;
        w[0] = (__bf16)v[0]; w[1] = (__bf16)v[1]; w[2] = (__bf16)v[2]; w[3] = (__bf16)v[3];
        *(bf16x4*)(A2 + r * KPAD + k) = w;
    }
#pragma unroll
    for (int j = 0; j < 2; ++j) {
        int idx = j * 256 + tid;
        int b4 = idx >> 7, c = idx & 127;
        gts[idx] = g_t[(((bq * 4 + b4) * TD + t) << 7) + c];
    }
    __syncthreads();

#pragma unroll
    for (int j = 0; j < 2; ++j) {
        int idx = j * 256 + tid;
        int b4 = idx >> 7, c = idx & 127;
        float s = 0.f;
        for (int nn = 0; nn < 64; ++nn) s += (float)A2[(b4 * 64 + nn) * KPAD + c];
        hm[idx] = s * (1.f / 64.f);
    }
    __syncthreads();

    for (int m = 0; m < 5; ++m) {
        const float* M = (m < 3) ? (Zg + ((size_t)(m * TD + t) << 14))
                                 : (Wg + ((size_t)((m - 2) * TD + t) << 14));
#pragma unroll
        for (int j = 0; j < 16; ++j) {
            int fid = j * 256 + tid;
            int k = fid >> 5, c4 = (fid & 31) << 2;
            f32x4 v = *(const f32x4*)(M + (k << 7) + c4);
            bf16x4 w;
            w[0] = (__bf16)v[0]; w[1] = (__bf16)v[1]; w[2] = (__bf16)v[2]; w[3] = (__bf16)v[3];
            *(bf16x4*)(Wb + k * KPAD + c4) = w;
        }
        __syncthreads();
        const float* vec = (m >= 3) ? hm : gts;
#pragma unroll
        for (int j = 0; j < 2; ++j) {
            int idx = j * 256 + tid;
            int b4 = idx >> 7, c = idx & 127;
            float s = 0.f;
            for (int k = 0; k < 128; ++k) s += vec[b4 * 128 + k] * (float)Wb[k * KPAD + c];
            dts[(m * 4 + b4) * 128 + c] = s;
        }
        __syncthreads();
    }

    {
        const float* M = Wg + ((size_t)t << 14);
#pragma unroll
        for (int j = 0; j < 16; ++j) {
            int fid = j * 256 + tid;
            int k = fid >> 5, q = fid & 31;
            f32x4 v = *(const f32x4*)(M + (k << 7) + q * 4);
            int cb = q * 4;
            Wb[(cb + 0) * KPAD + k] = (__bf16)v[0];
            Wb[(cb + 1) * KPAD + k] = (__bf16)v[1];
            Wb[(cb + 2) * KPAD + k] = (__bf16)v[2];
            Wb[(cb + 3) * KPAD + k] = (__bf16)v[3];
        }
        __syncthreads();
    }

    f32x4 acc[4][8];
    const f32x4 vzero = {0.f, 0.f, 0.f, 0.f};
#pragma unroll
    for (int mi = 0; mi < 4; ++mi)
#pragma unroll
        for (int ni = 0; ni < 8; ++ni) acc[mi][ni] = vzero;
#pragma unroll
    for (int ks = 0; ks < 4; ++ks) {
        int kb = ks * 32 + lg * 8;
        bf16x8 a[4];
#pragma unroll
        for (int mi = 0; mi < 4; ++mi)
            a[mi] = *(const bf16x8*)(A2 + (wv * 64 + mi * 16 + l16) * KPAD + kb);
#pragma unroll
        for (int ni = 0; ni < 8; ++ni) {
            bf16x8 bfr = *(const bf16x8*)(Wb + (ni * 16 + l16) * KPAD + kb);
#pragma unroll
            for (int mi = 0; mi < 4; ++mi)
                acc[mi][ni] = __builtin_amdgcn_mfma_f32_16x16x32_bf16(a[mi], bfr, acc[mi][ni], 0, 0, 0);
        }
    }

    int b = bq * 4 + wv, bt = b * TD + t;
#pragma unroll
    for (int ni = 0; ni < 8; ++ni) {
        int col = ni * 16 + l16;
        float z = dts[(0 * 4 + wv) * 128 + col] + bg[t * HD + col];
        float macc = 0.f;
#pragma unroll
        for (int mi = 0; mi < 4; ++mi) {
#pragma unroll
            for (int r = 0; r < 4; ++r) {
                int row = mi * 16 + lg * 4 + r;
                float f  = sigf(acc[mi][ni][r] + z);
                float cv = chn[((bt * ND + row) << 7) + col];
                macc += f * cv;
            }
        }
        macc += __shfl_xor(macc, 16, 64);
        macc += __shfl_xor(macc, 32, 64);
        if (lg == 0) {
            float Mn  = macc * (1.f / 64.f);
            float g_g = sigf(dts[(3 * 4 + wv) * 128 + col] + dts[(1 * 4 + wv) * 128 + col]
                             + bg[(TD + t) * HD + col]);
            float o_g = sigf(dts[(4 * 4 + wv) * 128 + col] + dts[(2 * 4 + wv) * 128 + col]
                             + bg[(2 * TD + t) * HD + col]);
            float cgt = c_g_t[(bt << 7) + col];
            float cgn = Mn + g_g * cgt;
            out[OUT_G  + (bt << 7) + col] = tanhf_fast(cgn) * o_g;
            out[OUT_CG + (bt << 7) + col] = cgn;
        }
    }
}

extern "C" void kernel_launch(void* const* d_in, const int* in_sizes, int n_in,
                              void* d_out, int out_size, void* d_ws, size_t ws_size,
                              hipStream_t stream) {
    const float* h     = (const float*)d_in[0];
    const float* c_h   = (const float*)d_in[1];
    const float* p     = (const float*)d_in[2];
    const float* g_t   = (const float*)d_in[3];
    const float* c_g_t = (const float*)d_in[4];
    const float* U     = (const float*)d_in[5];
    const float* Wt    = (const float*)d_in[6];
    const float* Ws    = (const float*)d_in[7];
    const float* Zt    = (const float*)d_in[8];
    const float* b     = (const float*)d_in[9];
    const float* Wg    = (const float*)d_in[10];
    const float* Zg    = (const float*)d_in[11];
    const float* bg    = (const float*)d_in[12];
    float* out = (float*)d_out;
    __bf16* ws = (__bf16*)d_ws;

    prep_actszb<<<NB_ACTS + NB_ZB, 256, 0, stream>>>(h, p, g_t, Zt, b, ws);
    prep_w<<<392 * 5, 256, 0, stream>>>(U, Wt, Ws, ws + WP_OFF);

    (void)hipFuncSetAttribute(reinterpret_cast<const void*>(phase1_kernel),
                              hipFuncAttributeMaxDynamicSharedMemorySize, LDS1_BYTES);
    (void)hipFuncSetAttribute(reinterpret_cast<const void*>(phase2_kernel),
                              hipFuncAttributeMaxDynamicSharedMemorySize, LDS2_BYTES);
    phase1_kernel<<<TD * 64, 256, LDS1_BYTES, stream>>>(ws, c_h, c_g_t, out);
    phase2_kernel<<<TD * 4, 256, LDS2_BYTES, stream>>>(g_t, c_g_t, Wg, Zg, bg, out);
}

// Round 11
// 269.864 us; speedup vs baseline: 1.3949x; 1.3949x over previous
//
#include <hip/hip_runtime.h>
#include <hip/hip_bf16.h>

#define TD 49
#define BD 16
#define ND 64
#define HD 128

typedef float  f32x4  __attribute__((ext_vector_type(4)));
typedef __bf16 bf16x8 __attribute__((ext_vector_type(8)));
typedef __bf16 bf16x4 __attribute__((ext_vector_type(4)));

// ---------------- workspace layout (bf16 element offsets) ----------------
// W' [t*8+g][h=128][k=640], k-order = [U | Wt0 | Wt1 | Wt2 | Ws]
#define WP_OFF   0u
#define HB_OFF   32112640u           // h  bf16 [B,T,N,H]
#define ACT_ELEMS 6422528u
#define PB_OFF   38535168u           // p  bf16
#define GB_OFF   44957696u           // g_t bf16 [B,T,H]
#define GT_ELEMS 100352u
#define ZP_OFF   45058048u           // 2048 bf16 zeros (pad source page)
#define ZB_OFF   45060096u           // f32 zb[b,t,g,h] = Zt.g_t + b  (802816 f32)

#define OUT_H    0
#define OUT_CH   6422528
#define OUT_G    12845056
#define OUT_CG   12945408

#define KPAD 136
#define LDS1_BYTES 65536             // 4 slots x (A 8KB + B 8KB) -> 2 blocks/CU
#define LDS2_BYTES 118784

#define NB_ACTS 12644
#define NB_ZB   392                  // 49*8

__device__ __forceinline__ float sigf(float x) {
    return 1.0f / (1.0f + exp2f(-1.442695041f * x));
}
__device__ __forceinline__ float tanhf_fast(float x) {
    x = fminf(fmaxf(x, -20.f), 20.f);
    float e = exp2f(2.885390082f * x);
    return (e - 1.f) / (e + 1.f);
}
__device__ __forceinline__ void gload16(const void* g, void* l) {
    __builtin_amdgcn_global_load_lds((const __attribute__((address_space(1))) void*)g,
                                     (__attribute__((address_space(3))) void*)l, 16, 0, 0);
}

// ---------------------------------------------------------------------------
// prep_actszb: [0,NB_ACTS) streaming cast h/p/g_t -> bf16 + zero page;
//              [NB_ACTS, +NB_ZB) zb[b,t,g,h] = sum_k g_t*Zt + bias (f32),
//              with g_t staged in LDS (fix for the 150us latency tail: the old
//              version did 8 global loads per k-iter, 1024 dependent loads).
// ---------------------------------------------------------------------------
__global__ __launch_bounds__(256) void prep_actszb(
    const float* __restrict__ h, const float* __restrict__ p,
    const float* __restrict__ g, const float* __restrict__ Zt,
    const float* __restrict__ bias, __bf16* __restrict__ ws)
{
    __shared__ float gl[16][128];
    const int bid = blockIdx.x;
    const int tid = threadIdx.x;

    if (bid < NB_ACTS) {
        unsigned i = bid * 256u + tid;
        const unsigned HU = ACT_ELEMS / 4u, GU = GT_ELEMS / 4u;
        const float* src;
        unsigned dst;
        if (i < HU)              { src = h + (size_t)i * 4;            dst = HB_OFF + i * 4; }
        else if (i < 2u*HU)      { unsigned j = i - HU;    src = p + (size_t)j * 4; dst = PB_OFF + j * 4; }
        else if (i < 2u*HU + GU) { unsigned j = i - 2u*HU; src = g + (size_t)j * 4; dst = GB_OFF + j * 4; }
        else if (i < 2u*HU + GU + 512u) {
            unsigned j = i - 2u*HU - GU;
            bf16x4 z = {};
            *(bf16x4*)(ws + ZP_OFF + j * 4) = z;
            return;
        } else return;
        f32x4 v = *(const f32x4*)src;
        bf16x4 w;
        w[0] = (__bf16)v[0]; w[1] = (__bf16)v[1]; w[2] = (__bf16)v[2]; w[3] = (__bf16)v[3];
        *(bf16x4*)(ws + dst) = w;
        return;
    }

    // ---- zb: block = (t, gate); g_t staged in LDS first
    {
        int zid = bid - NB_ACTS;
        int t = zid >> 3, gg = zid & 7;
#pragma unroll
        for (int j = 0; j < 8; ++j) {
            int idx = j * 256 + tid;            // [0,2048)
            int b = idx >> 7, k = idx & 127;
            gl[b][k] = g[((b * TD + t) << 7) + k];
        }
        __syncthreads();

        int h_ = tid & 127, bh = tid >> 7;      // 2 halves x 8 batches
        float* zbf = (float*)(ws + ZB_OFF);
        float s[8];
        float bv = bias[(gg * TD + t) * HD + h_];
#pragma unroll
        for (int b8 = 0; b8 < 8; ++b8) s[b8] = bv;
        const float* Zrow = Zt + ((size_t)(gg * TD + t) << 14) + h_;
#pragma unroll 4
        for (int k = 0; k < 128; ++k) {
            float zv = Zrow[k << 7];
#pragma unroll
            for (int b8 = 0; b8 < 8; ++b8)
                s[b8] += gl[bh * 8 + b8][k] * zv;
        }
#pragma unroll
        for (int b8 = 0; b8 < 8; ++b8) {
            int bt = (bh * 8 + b8) * TD + t;
            zbf[(bt * 8 + gg) * HD + h_] = s[b8];
        }
    }
}

// ---------------------------------------------------------------------------
// prep_w v2: register transpose, no LDS. Block = (tg, kc 128-k chunk); lane
// unit = one h-row x 8 k's: 8 strided f32 loads -> bf16x8 coalesced write.
// grid = 392 * 5.
// ---------------------------------------------------------------------------
__global__ __launch_bounds__(256) void prep_w(
    const float* __restrict__ U, const float* __restrict__ Wt,
    const float* __restrict__ Ws, __bf16* __restrict__ wp)
{
    int bid = blockIdx.x;
    int tg = bid / 5, kc = bid % 5;
    int t = tg >> 3, gg = tg & 7;
    int gt = gg * TD + t;
    const float* S;
    int kloc0;
    if (kc == 0)      { S = U  + ((size_t)gt << 14); kloc0 = 0; }
    else if (kc <= 3) { S = Wt + (size_t)gt * 49152; kloc0 = (kc - 1) * 128; }
    else              { S = Ws + ((size_t)gt << 14); kloc0 = 0; }
    int tid = threadIdx.x;
    __bf16* wrow = wp + (size_t)tg * 81920 + kc * 128;
#pragma unroll
    for (int u = 0; u < 8; ++u) {
        int gid = u * 256 + tid;              // [0,2048)
        int hh = gid >> 4, kq = gid & 15;
        const float* s = S + (size_t)(kloc0 + kq * 8) * 128 + hh;
        bf16x8 w;
#pragma unroll
        for (int j = 0; j < 8; ++j) w[j] = (__bf16)s[j * 128];
        *(bf16x8*)(wrow + (size_t)hh * 640 + kq * 8) = w;
    }
}

// ---------------------------------------------------------------------------
// Phase 1: 128x128 tile (M=128, N = 8 gates x 16 hcols), BK=32, K=640
// (20 steps), 4 LDS slots, depth-3 prefetch, counted vmcnt(8) + raw barrier.
// 4 waves, wave = 32 rows x all 8 gates (in-register gate epilogue, bias=zb).
// ---------------------------------------------------------------------------
__global__ __launch_bounds__(256, 2) void phase1_kernel(
    const __bf16* __restrict__ ws,
    const float* __restrict__ c_h, const float* __restrict__ c_g_t,
    float* __restrict__ out)
{
    extern __shared__ __bf16 smem[];     // A slots elems [0,16384); B: [16384,32768)
    const __bf16* hb = ws + HB_OFF;
    const __bf16* pb = ws + PB_OFF;
    const __bf16* wp = ws + WP_OFF;
    const __bf16* zp = ws + ZP_OFF;
    const float*  zb = (const float*)(ws + ZB_OFF);

    int bid = blockIdx.x;
    int swz = (bid & 7) * 392 + (bid >> 3);  // bijective, 3136 = 8*392
    int t     = swz >> 6;
    int rem   = swz & 63;
    int mtile = rem >> 3, ntile = rem & 7;

    int tid  = threadIdx.x;
    int wave = tid >> 6, lane = tid & 63;
    int lg = lane >> 4, l16 = lane & 15;

    // ---- staging maps: chunk = it*256+tid covers 16B of a slot
    const __bf16* pA[2][5];
    const __bf16* pB[2];
    int dstA[2], dstB[2];
#pragma unroll
    for (int it = 0; it < 2; ++it) {
        int chunk = it * 256 + tid;          // [0,512)
        int row   = chunk >> 2;              // [0,128)
        int k16   = chunk & 3;
        int ke    = (k16 ^ ((row >> 1) & 3)) * 8;   // swizzled k elem offset
        int b_ = mtile * 2 + (row >> 6), n_ = row & 63, bt_ = b_ * TD + t;
        pA[it][0] = pb + ((bt_ * ND + n_) << 7) + ke;
        pA[it][1] = (t > 0)      ? hb + (((bt_ - 1) * ND + n_) << 7) + ke : zp + ke;
        pA[it][2] = hb + ((bt_ * ND + n_) << 7) + ke;
        pA[it][3] = (t < TD - 1) ? hb + (((bt_ + 1) * ND + n_) << 7) + ke : zp + ke;
        pA[it][4] = (n_ > 0)     ? hb + ((bt_ * ND + n_ - 1) << 7) + ke : zp + ke;
        int g_ = row >> 4, hc = row & 15;
        pB[it] = wp + (size_t)((t * 8 + g_) * 128 + ntile * 16 + hc) * 640 + ke;
        dstA[it] = chunk * 8;
        dstB[it] = 16384 + chunk * 8;
    }

    // ---- fragment read byte-offsets (A within slot; B folded +32768 bytes)
    int rbA[2], rbB[8];
#pragma unroll
    for (int mi = 0; mi < 2; ++mi) {
        int row = wave * 32 + mi * 16 + l16;
        rbA[mi] = row * 64 + ((lg ^ ((row >> 1) & 3)) << 4);
    }
#pragma unroll
    for (int g = 0; g < 8; ++g) {
        int row = g * 16 + l16;
        rbB[g] = 32768 + row * 64 + ((lg ^ ((row >> 1) & 3)) << 4);
    }

    f32x4 acc[2][8];
    const f32x4 vzero = {0.f, 0.f, 0.f, 0.f};
#pragma unroll
    for (int mi = 0; mi < 2; ++mi)
#pragma unroll
        for (int g = 0; g < 8; ++g) acc[mi][g] = vzero;

#define STAGE(KS) do {                                                          \
        _Pragma("unroll")                                                       \
        for (int it = 0; it < 2; ++it) {                                        \
            gload16(pA[it][(KS) >> 2] + ((KS) & 3) * 32,                        \
                    smem + ((KS) & 3) * 4096 + dstA[it]);                       \
            gload16(pB[it] + (KS) * 32,                                         \
                    smem + ((KS) & 3) * 4096 + dstB[it]);                       \
        }                                                                       \
    } while (0)

    STAGE(0); STAGE(1); STAGE(2);
    asm volatile("s_waitcnt vmcnt(8)" ::: "memory");   // tile 0 landed (1,2 in flight)
    __builtin_amdgcn_s_barrier();

#pragma unroll
    for (int ks = 0; ks < 20; ++ks) {
        if (ks + 3 < 20) STAGE(ks + 3);
        const char* base = (const char*)smem + (ks & 3) * 8192;
        bf16x8 af[2], bfr[8];
        af[0] = *(const bf16x8*)(base + rbA[0]);
        af[1] = *(const bf16x8*)(base + rbA[1]);
#pragma unroll
        for (int g = 0; g < 8; ++g)
            bfr[g] = *(const bf16x8*)(base + rbB[g]);
#pragma unroll
        for (int g = 0; g < 8; ++g) {
            acc[0][g] = __builtin_amdgcn_mfma_f32_16x16x32_bf16(af[0], bfr[g], acc[0][g], 0, 0, 0);
            acc[1][g] = __builtin_amdgcn_mfma_f32_16x16x32_bf16(af[1], bfr[g], acc[1][g], 0, 0, 0);
        }
        if (ks < 19) {
            if (ks < 17)       asm volatile("s_waitcnt vmcnt(8)" ::: "memory");
            else if (ks == 17) asm volatile("s_waitcnt vmcnt(4)" ::: "memory");
            else               asm volatile("s_waitcnt vmcnt(0)" ::: "memory");
            __builtin_amdgcn_s_barrier();
        }
    }
#undef STAGE

    // ---- epilogue: gates + cell update; bias comes from precomputed zb ----
    const int hcol = ntile * 16 + l16;
#pragma unroll
    for (int mi = 0; mi < 2; ++mi) {
#pragma unroll
        for (int r = 0; r < 4; ++r) {
            int RG = mtile * 128 + wave * 32 + mi * 16 + lg * 4 + r;
            int b  = RG >> 6, nn = RG & 63;
            int bt = b * TD + t;
            int base = ((bt * ND + nn) << 7) + hcol;
            const float* zrow = zb + (bt * 8) * HD + hcol;
            float pre[8];
#pragma unroll
            for (int g = 0; g < 8; ++g) pre[g] = acc[mi][g][r] + zrow[g * HD];
            float i_  = sigf(pre[0]);
            float flt = sigf(pre[1]);
            float fft = sigf(pre[2]);
            float frt = sigf(pre[3]);
            float fs  = sigf(pre[4]);
            float gn  = sigf(pre[5]);
            float on  = sigf(pre[6]);
            float cn  = tanhf_fast(pre[7]);
            float ccur = c_h[base];
            float ctb  = (t > 0)      ? c_h[base - ND * HD] : 0.f;
            float cta  = (t < TD - 1) ? c_h[base + ND * HD] : 0.f;
            float csb  = (nn > 0)     ? c_h[base - HD]      : 0.f;
            float cg   = c_g_t[(bt << 7) + hcol];
            float cnew = i_ * cn + flt * ctb + fft * ccur + frt * cta + fs * csb + gn * cg;
            float hnew = on * tanhf_fast(cnew);
            out[OUT_H  + base] = hnew;
            out[OUT_CH + base] = cnew;
        }
    }
}

// ---------------------------------------------------------------------------
// Phase 2: grid 49 t x 4 bq; block = 4 b's (1 wave each). Stages the six
// 128x128 matrices ONCE per block. hm from staged h_new; f_gtf via MFMA.
// ---------------------------------------------------------------------------
__global__ __launch_bounds__(256, 1) void phase2_kernel(
    const float* __restrict__ g_t, const float* __restrict__ c_g_t,
    const float* __restrict__ Wg,  const float* __restrict__ Zg,
    const float* __restrict__ bg,  float* __restrict__ out)
{
    extern __shared__ char sm2[];
    __bf16* A2  = (__bf16*)sm2;                       // [256][136] h_new bf16
    __bf16* Wb  = (__bf16*)(sm2 + 69632);             // [128][136] staging
    float*  gts = (float*)(sm2 + 69632 + 34816);      // [4][128]
    float*  hm  = (float*)(sm2 + 69632 + 34816 + 2048);
    float*  dts = (float*)(sm2 + 69632 + 34816 + 4096); // [5][4][128]

    int bid = blockIdx.x;
    int t = bid >> 2, bq = bid & 3;
    int tid = threadIdx.x;
    int wv = tid >> 6, lane = tid & 63, lg = lane >> 4, l16 = lane & 15;

    const float* hn  = out + OUT_H;
    const float* chn = out + OUT_CH;

#pragma unroll
    for (int j = 0; j < 32; ++j) {
        int fid = j * 256 + tid;
        int r = fid >> 5, k = (fid & 31) << 2;
        int b = bq * 4 + (r >> 6), nn = r & 63, bt = b * TD + t;
        f32x4 v = *(const f32x4*)(hn + ((bt * ND + nn) << 7) + k);
        bf16x4 w;
        w[0] = (__bf16)v[0]; w[1] = (__bf16)v[1]; w[2] = (__bf16)v[2]; w[3] = (__bf16)v[3];
        *(bf16x4*)(A2 + r * KPAD + k) = w;
    }
#pragma unroll
    for (int j = 0; j < 2; ++j) {
        int idx = j * 256 + tid;
        int b4 = idx >> 7, c = idx & 127;
        gts[idx] = g_t[(((bq * 4 + b4) * TD + t) << 7) + c];
    }
    __syncthreads();

#pragma unroll
    for (int j = 0; j < 2; ++j) {
        int idx = j * 256 + tid;
        int b4 = idx >> 7, c = idx & 127;
        float s = 0.f;
        for (int nn = 0; nn < 64; ++nn) s += (float)A2[(b4 * 64 + nn) * KPAD + c];
        hm[idx] = s * (1.f / 64.f);
    }
    __syncthreads();

    for (int m = 0; m < 5; ++m) {
        const float* M = (m < 3) ? (Zg + ((size_t)(m * TD + t) << 14))
                                 : (Wg + ((size_t)((m - 2) * TD + t) << 14));
#pragma unroll
        for (int j = 0; j < 16; ++j) {
            int fid = j * 256 + tid;
            int k = fid >> 5, c4 = (fid & 31) << 2;
            f32x4 v = *(const f32x4*)(M + (k << 7) + c4);
            bf16x4 w;
            w[0] = (__bf16)v[0]; w[1] = (__bf16)v[1]; w[2] = (__bf16)v[2]; w[3] = (__bf16)v[3];
            *(bf16x4*)(Wb + k * KPAD + c4) = w;
        }
        __syncthreads();
        const float* vec = (m >= 3) ? hm : gts;
#pragma unroll
        for (int j = 0; j < 2; ++j) {
            int idx = j * 256 + tid;
            int b4 = idx >> 7, c = idx & 127;
            float s = 0.f;
            for (int k = 0; k < 128; ++k) s += vec[b4 * 128 + k] * (float)Wb[k * KPAD + c];
            dts[(m * 4 + b4) * 128 + c] = s;
        }
        __syncthreads();
    }

    {
        const float* M = Wg + ((size_t)t << 14);
#pragma unroll
        for (int j = 0; j < 16; ++j) {
            int fid = j * 256 + tid;
            int k = fid >> 5, q = fid & 31;
            f32x4 v = *(const f32x4*)(M + (k << 7) + q * 4);
            int cb = q * 4;
            Wb[(cb + 0) * KPAD + k] = (__bf16)v[0];
            Wb[(cb + 1) * KPAD + k] = (__bf16)v[1];
            Wb[(cb + 2) * KPAD + k] = (__bf16)v[2];
            Wb[(cb + 3) * KPAD + k] = (__bf16)v[3];
        }
        __syncthreads();
    }

    f32x4 acc[4][8];
    const f32x4 vzero = {0.f, 0.f, 0.f, 0.f};
#pragma unroll
    for (int mi = 0; mi < 4; ++mi)
#pragma unroll
        for (int ni = 0; ni < 8; ++ni) acc[mi][ni] = vzero;
#pragma unroll
    for (int ks = 0; ks < 4; ++ks) {
        int kb = ks * 32 + lg * 8;
        bf16x8 a[4];
#pragma unroll
        for (int mi = 0; mi < 4; ++mi)
            a[mi] = *(const bf16x8*)(A2 + (wv * 64 + mi * 16 + l16) * KPAD + kb);
#pragma unroll
        for (int ni = 0; ni < 8; ++ni) {
            bf16x8 bfr = *(const bf16x8*)(Wb + (ni * 16 + l16) * KPAD + kb);
#pragma unroll
            for (int mi = 0; mi < 4; ++mi)
                acc[mi][ni] = __builtin_amdgcn_mfma_f32_16x16x32_bf16(a[mi], bfr, acc[mi][ni], 0, 0, 0);
        }
    }

    int b = bq * 4 + wv, bt = b * TD + t;
#pragma unroll
    for (int ni = 0; ni < 8; ++ni) {
        int col = ni * 16 + l16;
        float z = dts[(0 * 4 + wv) * 128 + col] + bg[t * HD + col];
        float macc = 0.f;
#pragma unroll
        for (int mi = 0; mi < 4; ++mi) {
#pragma unroll
            for (int r = 0; r < 4; ++r) {
                int row = mi * 16 + lg * 4 + r;
                float f  = sigf(acc[mi][ni][r] + z);
                float cv = chn[((bt * ND + row) << 7) + col];
                macc += f * cv;
            }
        }
        macc += __shfl_xor(macc, 16, 64);
        macc += __shfl_xor(macc, 32, 64);
        if (lg == 0) {
            float Mn  = macc * (1.f / 64.f);
            float g_g = sigf(dts[(3 * 4 + wv) * 128 + col] + dts[(1 * 4 + wv) * 128 + col]
                             + bg[(TD + t) * HD + col]);
            float o_g = sigf(dts[(4 * 4 + wv) * 128 + col] + dts[(2 * 4 + wv) * 128 + col]
                             + bg[(2 * TD + t) * HD + col]);
            float cgt = c_g_t[(bt << 7) + col];
            float cgn = Mn + g_g * cgt;
            out[OUT_G  + (bt << 7) + col] = tanhf_fast(cgn) * o_g;
            out[OUT_CG + (bt << 7) + col] = cgn;
        }
    }
}

extern "C" void kernel_launch(void* const* d_in, const int* in_sizes, int n_in,
                              void* d_out, int out_size, void* d_ws, size_t ws_size,
                              hipStream_t stream) {
    const float* h     = (const float*)d_in[0];
    const float* c_h   = (const float*)d_in[1];
    const float* p     = (const float*)d_in[2];
    const float* g_t   = (const float*)d_in[3];
    const float* c_g_t = (const float*)d_in[4];
    const float* U     = (const float*)d_in[5];
    const float* Wt    = (const float*)d_in[6];
    const float* Ws    = (const float*)d_in[7];
    const float* Zt    = (const float*)d_in[8];
    const float* b     = (const float*)d_in[9];
    const float* Wg    = (const float*)d_in[10];
    const float* Zg    = (const float*)d_in[11];
    const float* bg    = (const float*)d_in[12];
    float* out = (float*)d_out;
    __bf16* ws = (__bf16*)d_ws;

    prep_actszb<<<NB_ACTS + NB_ZB, 256, 0, stream>>>(h, p, g_t, Zt, b, ws);
    prep_w<<<392 * 5, 256, 0, stream>>>(U, Wt, Ws, ws + WP_OFF);

    (void)hipFuncSetAttribute(reinterpret_cast<const void*>(phase1_kernel),
                              hipFuncAttributeMaxDynamicSharedMemorySize, LDS1_BYTES);
    (void)hipFuncSetAttribute(reinterpret_cast<const void*>(phase2_kernel),
                              hipFuncAttributeMaxDynamicSharedMemorySize, LDS2_BYTES);
    phase1_kernel<<<TD * 64, 256, LDS1_BYTES, stream>>>(ws, c_h, c_g_t, out);
    phase2_kernel<<<TD * 4, 256, LDS2_BYTES, stream>>>(g_t, c_g_t, Wg, Zg, bg, out);
}

// Round 12
// 254.285 us; speedup vs baseline: 1.4804x; 1.0613x over previous
//
#include <hip/hip_runtime.h>
#include <hip/hip_bf16.h>

#define TD 49
#define BD 16
#define ND 64
#define HD 128

typedef float  f32x4  __attribute__((ext_vector_type(4)));
typedef __bf16 bf16x8 __attribute__((ext_vector_type(8)));
typedef __bf16 bf16x4 __attribute__((ext_vector_type(4)));

// ---------------- workspace layout (bf16 element offsets) ----------------
// W' [t*8+g][h=128][k=640], k-order = [U | Wt0 | Wt1 | Wt2 | Ws]
#define WP_OFF   0u
#define HB_OFF   32112640u           // h  bf16 [B,T,N,H]
#define ACT_ELEMS 6422528u
#define PB_OFF   38535168u           // p  bf16
#define GB_OFF   44957696u           // g_t bf16 [B,T,H]
#define GT_ELEMS 100352u
#define ZP_OFF   45058048u           // 2048 bf16 zeros (pad source page)
#define ZB_OFF   45060096u           // f32 zb[b,t,g,h] = Zt.g_t + b  (802816 f32)

#define OUT_H    0
#define OUT_CH   6422528
#define OUT_G    12845056
#define OUT_CG   12945408

#define KPAD 136
#define LDS1_BYTES 49152             // 3 slots x (A 8KB + B 8KB) -> 3 blocks/CU
#define LDS2_BYTES 118784

#define NB_ACTS 12644
#define NB_ZB   392                  // 49*8
#define NB_W    1960                 // 392*5

__device__ __forceinline__ float sigf(float x) {
    return 1.0f / (1.0f + exp2f(-1.442695041f * x));
}
__device__ __forceinline__ float tanhf_fast(float x) {
    x = fminf(fmaxf(x, -20.f), 20.f);
    float e = exp2f(2.885390082f * x);
    return (e - 1.f) / (e + 1.f);
}
__device__ __forceinline__ void gload16(const void* g, void* l) {
    __builtin_amdgcn_global_load_lds((const __attribute__((address_space(1))) void*)g,
                                     (__attribute__((address_space(3))) void*)l, 16, 0, 0);
}

// ---------------------------------------------------------------------------
// prep (merged): [0,NB_ACTS) streaming casts; [.., +NB_ZB) zb via LDS-staged
// g_t; [.., +NB_W) weight transpose (register, no LDS).
// ---------------------------------------------------------------------------
__global__ __launch_bounds__(256) void prep_kernel(
    const float* __restrict__ h, const float* __restrict__ p,
    const float* __restrict__ g, const float* __restrict__ Zt,
    const float* __restrict__ bias, const float* __restrict__ U,
    const float* __restrict__ Wt, const float* __restrict__ Ws,
    __bf16* __restrict__ ws)
{
    __shared__ float gl[16][128];
    const int bid = blockIdx.x;
    const int tid = threadIdx.x;

    if (bid < NB_ACTS) {
        unsigned i = bid * 256u + tid;
        const unsigned HU = ACT_ELEMS / 4u, GU = GT_ELEMS / 4u;
        const float* src;
        unsigned dst;
        if (i < HU)              { src = h + (size_t)i * 4;            dst = HB_OFF + i * 4; }
        else if (i < 2u*HU)      { unsigned j = i - HU;    src = p + (size_t)j * 4; dst = PB_OFF + j * 4; }
        else if (i < 2u*HU + GU) { unsigned j = i - 2u*HU; src = g + (size_t)j * 4; dst = GB_OFF + j * 4; }
        else if (i < 2u*HU + GU + 512u) {
            unsigned j = i - 2u*HU - GU;
            bf16x4 z = {};
            *(bf16x4*)(ws + ZP_OFF + j * 4) = z;
            return;
        } else return;
        f32x4 v = *(const f32x4*)src;
        bf16x4 w;
        w[0] = (__bf16)v[0]; w[1] = (__bf16)v[1]; w[2] = (__bf16)v[2]; w[3] = (__bf16)v[3];
        *(bf16x4*)(ws + dst) = w;
        return;
    }

    if (bid < NB_ACTS + NB_ZB) {
        // ---- zb: block = (t, gate); g_t staged in LDS first
        int zid = bid - NB_ACTS;
        int t = zid >> 3, gg = zid & 7;
#pragma unroll
        for (int j = 0; j < 8; ++j) {
            int idx = j * 256 + tid;            // [0,2048)
            int b = idx >> 7, k = idx & 127;
            gl[b][k] = g[((b * TD + t) << 7) + k];
        }
        __syncthreads();

        int h_ = tid & 127, bh = tid >> 7;      // 2 halves x 8 batches
        float* zbf = (float*)(ws + ZB_OFF);
        float s[8];
        float bv = bias[(gg * TD + t) * HD + h_];
#pragma unroll
        for (int b8 = 0; b8 < 8; ++b8) s[b8] = bv;
        const float* Zrow = Zt + ((size_t)(gg * TD + t) << 14) + h_;
#pragma unroll 4
        for (int k = 0; k < 128; ++k) {
            float zv = Zrow[k << 7];
#pragma unroll
            for (int b8 = 0; b8 < 8; ++b8)
                s[b8] += gl[bh * 8 + b8][k] * zv;
        }
#pragma unroll
        for (int b8 = 0; b8 < 8; ++b8) {
            int bt = (bh * 8 + b8) * TD + t;
            zbf[(bt * 8 + gg) * HD + h_] = s[b8];
        }
        return;
    }

    // ---- prep_w: register transpose, no LDS
    {
        int wb = bid - NB_ACTS - NB_ZB;
        int tg = wb / 5, kc = wb % 5;
        int t = tg >> 3, gg = tg & 7;
        int gt = gg * TD + t;
        const float* S;
        int kloc0;
        if (kc == 0)      { S = U  + ((size_t)gt << 14); kloc0 = 0; }
        else if (kc <= 3) { S = Wt + (size_t)gt * 49152; kloc0 = (kc - 1) * 128; }
        else              { S = Ws + ((size_t)gt << 14); kloc0 = 0; }
        __bf16* wrow = ws + WP_OFF + (size_t)tg * 81920 + kc * 128;
#pragma unroll
        for (int u = 0; u < 8; ++u) {
            int gid = u * 256 + tid;              // [0,2048)
            int hh = gid >> 4, kq = gid & 15;
            const float* s = S + (size_t)(kloc0 + kq * 8) * 128 + hh;
            bf16x8 w;
#pragma unroll
            for (int j = 0; j < 8; ++j) w[j] = (__bf16)s[j * 128];
            *(bf16x8*)(wrow + (size_t)hh * 640 + kq * 8) = w;
        }
    }
}

// ---------------------------------------------------------------------------
// Phase 1: 128x128 tile (M=128, N = 8 gates x 16 hcols), BK=32, K=640
// (20 steps), 3 LDS slots (48KB -> 3 blocks/CU), depth-2 prefetch, counted
// vmcnt(4) + raw barrier. 4 waves, wave = 32 rows x all 8 gates.
// Slot math: step ks stages tile ks+2 into slot (ks+2)%3 == (ks-1)%3 (freed
// by end-of-(ks-1) barrier); vmcnt(4) at step end => tile ks+1 landed.
// ---------------------------------------------------------------------------
__global__ __launch_bounds__(256, 3) void phase1_kernel(
    const __bf16* __restrict__ ws,
    const float* __restrict__ c_h, const float* __restrict__ c_g_t,
    float* __restrict__ out)
{
    extern __shared__ __bf16 smem[];   // A slots: elems [0,12288); B: [12288,24576)
    const __bf16* hb = ws + HB_OFF;
    const __bf16* pb = ws + PB_OFF;
    const __bf16* wp = ws + WP_OFF;
    const __bf16* zp = ws + ZP_OFF;
    const float*  zb = (const float*)(ws + ZB_OFF);

    int bid = blockIdx.x;
    int swz = (bid & 7) * 392 + (bid >> 3);  // bijective, 3136 = 8*392
    int t     = swz >> 6;
    int rem   = swz & 63;
    int mtile = rem >> 3, ntile = rem & 7;

    int tid  = threadIdx.x;
    int wave = tid >> 6, lane = tid & 63;
    int lg = lane >> 4, l16 = lane & 15;

    // ---- staging maps: chunk = it*256+tid covers 16B of a slot
    const __bf16* pA[2][5];
    const __bf16* pB[2];
    int dstA[2], dstB[2];
#pragma unroll
    for (int it = 0; it < 2; ++it) {
        int chunk = it * 256 + tid;          // [0,512)
        int row   = chunk >> 2;              // [0,128)
        int k16   = chunk & 3;
        int ke    = (k16 ^ ((row >> 1) & 3)) * 8;   // swizzled k elem offset
        int b_ = mtile * 2 + (row >> 6), n_ = row & 63, bt_ = b_ * TD + t;
        pA[it][0] = pb + ((bt_ * ND + n_) << 7) + ke;
        pA[it][1] = (t > 0)      ? hb + (((bt_ - 1) * ND + n_) << 7) + ke : zp + ke;
        pA[it][2] = hb + ((bt_ * ND + n_) << 7) + ke;
        pA[it][3] = (t < TD - 1) ? hb + (((bt_ + 1) * ND + n_) << 7) + ke : zp + ke;
        pA[it][4] = (n_ > 0)     ? hb + ((bt_ * ND + n_ - 1) << 7) + ke : zp + ke;
        int g_ = row >> 4, hc = row & 15;
        pB[it] = wp + (size_t)((t * 8 + g_) * 128 + ntile * 16 + hc) * 640 + ke;
        dstA[it] = chunk * 8;                // elems within A slot
        dstB[it] = 12288 + chunk * 8;        // B region base (elems) + chunk
    }

    // ---- fragment read byte-offsets within a slot
    int rbA[2], rbB[8];
#pragma unroll
    for (int mi = 0; mi < 2; ++mi) {
        int row = wave * 32 + mi * 16 + l16;
        rbA[mi] = row * 64 + ((lg ^ ((row >> 1) & 3)) << 4);
    }
#pragma unroll
    for (int g = 0; g < 8; ++g) {
        int row = g * 16 + l16;
        rbB[g] = row * 64 + ((lg ^ ((row >> 1) & 3)) << 4);
    }

    f32x4 acc[2][8];
    const f32x4 vzero = {0.f, 0.f, 0.f, 0.f};
#pragma unroll
    for (int mi = 0; mi < 2; ++mi)
#pragma unroll
        for (int g = 0; g < 8; ++g) acc[mi][g] = vzero;

#define STAGE(KS) do {                                                          \
        const int sl = (KS) % 3;                                                \
        _Pragma("unroll")                                                       \
        for (int it = 0; it < 2; ++it) {                                        \
            gload16(pA[it][(KS) >> 2] + ((KS) & 3) * 32,                        \
                    smem + sl * 4096 + dstA[it]);                               \
            gload16(pB[it] + (KS) * 32,                                         \
                    smem + sl * 4096 + dstB[it]);                               \
        }                                                                       \
    } while (0)

    STAGE(0); STAGE(1);
    asm volatile("s_waitcnt vmcnt(4)" ::: "memory");   // tile 0 landed (1 in flight)
    __builtin_amdgcn_s_barrier();

#pragma unroll
    for (int ks = 0; ks < 20; ++ks) {
        if (ks + 2 < 20) STAGE(ks + 2);
        const char* Ab = (const char*)smem + (ks % 3) * 8192;
        const char* Bb = (const char*)smem + 24576 + (ks % 3) * 8192;
        bf16x8 af[2], bfr[8];
        af[0] = *(const bf16x8*)(Ab + rbA[0]);
        af[1] = *(const bf16x8*)(Ab + rbA[1]);
#pragma unroll
        for (int g = 0; g < 8; ++g)
            bfr[g] = *(const bf16x8*)(Bb + rbB[g]);
#pragma unroll
        for (int g = 0; g < 8; ++g) {
            acc[0][g] = __builtin_amdgcn_mfma_f32_16x16x32_bf16(af[0], bfr[g], acc[0][g], 0, 0, 0);
            acc[1][g] = __builtin_amdgcn_mfma_f32_16x16x32_bf16(af[1], bfr[g], acc[1][g], 0, 0, 0);
        }
        if (ks < 19) {
            if (ks + 2 < 20) asm volatile("s_waitcnt vmcnt(4)" ::: "memory");
            else             asm volatile("s_waitcnt vmcnt(0)" ::: "memory");
            __builtin_amdgcn_s_barrier();
        }
    }
#undef STAGE

    // ---- epilogue: gates + cell update; bias comes from precomputed zb ----
    const int hcol = ntile * 16 + l16;
#pragma unroll
    for (int mi = 0; mi < 2; ++mi) {
#pragma unroll
        for (int r = 0; r < 4; ++r) {
            int RG = mtile * 128 + wave * 32 + mi * 16 + lg * 4 + r;
            int b  = RG >> 6, nn = RG & 63;
            int bt = b * TD + t;
            int base = ((bt * ND + nn) << 7) + hcol;
            const float* zrow = zb + (bt * 8) * HD + hcol;
            float pre[8];
#pragma unroll
            for (int g = 0; g < 8; ++g) pre[g] = acc[mi][g][r] + zrow[g * HD];
            float i_  = sigf(pre[0]);
            float flt = sigf(pre[1]);
            float fft = sigf(pre[2]);
            float frt = sigf(pre[3]);
            float fs  = sigf(pre[4]);
            float gn  = sigf(pre[5]);
            float on  = sigf(pre[6]);
            float cn  = tanhf_fast(pre[7]);
            float ccur = c_h[base];
            float ctb  = (t > 0)      ? c_h[base - ND * HD] : 0.f;
            float cta  = (t < TD - 1) ? c_h[base + ND * HD] : 0.f;
            float csb  = (nn > 0)     ? c_h[base - HD]      : 0.f;
            float cg   = c_g_t[(bt << 7) + hcol];
            float cnew = i_ * cn + flt * ctb + fft * ccur + frt * cta + fs * csb + gn * cg;
            float hnew = on * tanhf_fast(cnew);
            out[OUT_H  + base] = hnew;
            out[OUT_CH + base] = cnew;
        }
    }
}

// ---------------------------------------------------------------------------
// Phase 2: grid 49 t x 4 bq; block = 4 b's (1 wave each). Stages the six
// 128x128 matrices ONCE per block. hm from staged h_new; f_gtf via MFMA.
// ---------------------------------------------------------------------------
__global__ __launch_bounds__(256, 1) void phase2_kernel(
    const float* __restrict__ g_t, const float* __restrict__ c_g_t,
    const float* __restrict__ Wg,  const float* __restrict__ Zg,
    const float* __restrict__ bg,  float* __restrict__ out)
{
    extern __shared__ char sm2[];
    __bf16* A2  = (__bf16*)sm2;                       // [256][136] h_new bf16
    __bf16* Wb  = (__bf16*)(sm2 + 69632);             // [128][136] staging
    float*  gts = (float*)(sm2 + 69632 + 34816);      // [4][128]
    float*  hm  = (float*)(sm2 + 69632 + 34816 + 2048);
    float*  dts = (float*)(sm2 + 69632 + 34816 + 4096); // [5][4][128]

    int bid = blockIdx.x;
    int t = bid >> 2, bq = bid & 3;
    int tid = threadIdx.x;
    int wv = tid >> 6, lane = tid & 63, lg = lane >> 4, l16 = lane & 15;

    const float* hn  = out + OUT_H;
    const float* chn = out + OUT_CH;

#pragma unroll
    for (int j = 0; j < 32; ++j) {
        int fid = j * 256 + tid;
        int r = fid >> 5, k = (fid & 31) << 2;
        int b = bq * 4 + (r >> 6), nn = r & 63, bt = b * TD + t;
        f32x4 v = *(const f32x4*)(hn + ((bt * ND + nn) << 7) + k);
        bf16x4 w;
        w[0] = (__bf16)v[0]; w[1] = (__bf16)v[1]; w[2] = (__bf16)v[2]; w[3] = (__bf16)v[3];
        *(bf16x4*)(A2 + r * KPAD + k) = w;
    }
#pragma unroll
    for (int j = 0; j < 2; ++j) {
        int idx = j * 256 + tid;
        int b4 = idx >> 7, c = idx & 127;
        gts[idx] = g_t[(((bq * 4 + b4) * TD + t) << 7) + c];
    }
    __syncthreads();

#pragma unroll
    for (int j = 0; j < 2; ++j) {
        int idx = j * 256 + tid;
        int b4 = idx >> 7, c = idx & 127;
        float s = 0.f;
        for (int nn = 0; nn < 64; ++nn) s += (float)A2[(b4 * 64 + nn) * KPAD + c];
        hm[idx] = s * (1.f / 64.f);
    }
    __syncthreads();

    for (int m = 0; m < 5; ++m) {
        const float* M = (m < 3) ? (Zg + ((size_t)(m * TD + t) << 14))
                                 : (Wg + ((size_t)((m - 2) * TD + t) << 14));
#pragma unroll
        for (int j = 0; j < 16; ++j) {
            int fid = j * 256 + tid;
            int k = fid >> 5, c4 = (fid & 31) << 2;
            f32x4 v = *(const f32x4*)(M + (k << 7) + c4);
            bf16x4 w;
            w[0] = (__bf16)v[0]; w[1] = (__bf16)v[1]; w[2] = (__bf16)v[2]; w[3] = (__bf16)v[3];
            *(bf16x4*)(Wb + k * KPAD + c4) = w;
        }
        __syncthreads();
        const float* vec = (m >= 3) ? hm : gts;
#pragma unroll
        for (int j = 0; j < 2; ++j) {
            int idx = j * 256 + tid;
            int b4 = idx >> 7, c = idx & 127;
            float s = 0.f;
            for (int k = 0; k < 128; ++k) s += vec[b4 * 128 + k] * (float)Wb[k * KPAD + c];
            dts[(m * 4 + b4) * 128 + c] = s;
        }
        __syncthreads();
    }

    {
        const float* M = Wg + ((size_t)t << 14);
#pragma unroll
        for (int j = 0; j < 16; ++j) {
            int fid = j * 256 + tid;
            int k = fid >> 5, q = fid & 31;
            f32x4 v = *(const f32x4*)(M + (k << 7) + q * 4);
            int cb = q * 4;
            Wb[(cb + 0) * KPAD + k] = (__bf16)v[0];
            Wb[(cb + 1) * KPAD + k] = (__bf16)v[1];
            Wb[(cb + 2) * KPAD + k] = (__bf16)v[2];
            Wb[(cb + 3) * KPAD + k] = (__bf16)v[3];
        }
        __syncthreads();
    }

    f32x4 acc[4][8];
    const f32x4 vzero = {0.f, 0.f, 0.f, 0.f};
#pragma unroll
    for (int mi = 0; mi < 4; ++mi)
#pragma unroll
        for (int ni = 0; ni < 8; ++ni) acc[mi][ni] = vzero;
#pragma unroll
    for (int ks = 0; ks < 4; ++ks) {
        int kb = ks * 32 + lg * 8;
        bf16x8 a[4];
#pragma unroll
        for (int mi = 0; mi < 4; ++mi)
            a[mi] = *(const bf16x8*)(A2 + (wv * 64 + mi * 16 + l16) * KPAD + kb);
#pragma unroll
        for (int ni = 0; ni < 8; ++ni) {
            bf16x8 bfr = *(const bf16x8*)(Wb + (ni * 16 + l16) * KPAD + kb);
#pragma unroll
            for (int mi = 0; mi < 4; ++mi)
                acc[mi][ni] = __builtin_amdgcn_mfma_f32_16x16x32_bf16(a[mi], bfr, acc[mi][ni], 0, 0, 0);
        }
    }

    int b = bq * 4 + wv, bt = b * TD + t;
#pragma unroll
    for (int ni = 0; ni < 8; ++ni) {
        int col = ni * 16 + l16;
        float z = dts[(0 * 4 + wv) * 128 + col] + bg[t * HD + col];
        float macc = 0.f;
#pragma unroll
        for (int mi = 0; mi < 4; ++mi) {
#pragma unroll
            for (int r = 0; r < 4; ++r) {
                int row = mi * 16 + lg * 4 + r;
                float f  = sigf(acc[mi][ni][r] + z);
                float cv = chn[((bt * ND + row) << 7) + col];
                macc += f * cv;
            }
        }
        macc += __shfl_xor(macc, 16, 64);
        macc += __shfl_xor(macc, 32, 64);
        if (lg == 0) {
            float Mn  = macc * (1.f / 64.f);
            float g_g = sigf(dts[(3 * 4 + wv) * 128 + col] + dts[(1 * 4 + wv) * 128 + col]
                             + bg[(TD + t) * HD + col]);
            float o_g = sigf(dts[(4 * 4 + wv) * 128 + col] + dts[(2 * 4 + wv) * 128 + col]
                             + bg[(2 * TD + t) * HD + col]);
            float cgt = c_g_t[(bt << 7) + col];
            float cgn = Mn + g_g * cgt;
            out[OUT_G  + (bt << 7) + col] = tanhf_fast(cgn) * o_g;
            out[OUT_CG + (bt << 7) + col] = cgn;
        }
    }
}

extern "C" void kernel_launch(void* const* d_in, const int* in_sizes, int n_in,
                              void* d_out, int out_size, void* d_ws, size_t ws_size,
                              hipStream_t stream) {
    const float* h     = (const float*)d_in[0];
    const float* c_h   = (const float*)d_in[1];
    const float* p     = (const float*)d_in[2];
    const float* g_t   = (const float*)d_in[3];
    const float* c_g_t = (const float*)d_in[4];
    const float* U     = (const float*)d_in[5];
    const float* Wt    = (const float*)d_in[6];
    const float* Ws    = (const float*)d_in[7];
    const float* Zt    = (const float*)d_in[8];
    const float* b     = (const float*)d_in[9];
    const float* Wg    = (const float*)d_in[10];
    const float* Zg    = (const float*)d_in[11];
    const float* bg    = (const float*)d_in[12];
    float* out = (float*)d_out;
    __bf16* ws = (__bf16*)d_ws;

    prep_kernel<<<NB_ACTS + NB_ZB + NB_W, 256, 0, stream>>>(h, p, g_t, Zt, b, U, Wt, Ws, ws);

    (void)hipFuncSetAttribute(reinterpret_cast<const void*>(phase1_kernel),
                              hipFuncAttributeMaxDynamicSharedMemorySize, LDS1_BYTES);
    (void)hipFuncSetAttribute(reinterpret_cast<const void*>(phase2_kernel),
                              hipFuncAttributeMaxDynamicSharedMemorySize, LDS2_BYTES);
    phase1_kernel<<<TD * 64, 256, LDS1_BYTES, stream>>>(ws, c_h, c_g_t, out);
    phase2_kernel<<<TD * 4, 256, LDS2_BYTES, stream>>>(g_t, c_g_t, Wg, Zg, bg, out);
}

// Round 13
// 246.264 us; speedup vs baseline: 1.5286x; 1.0326x over previous
//
#include <hip/hip_runtime.h>
#include <hip/hip_bf16.h>

#define TD 49
#define BD 16
#define ND 64
#define HD 128

typedef float  f32x4  __attribute__((ext_vector_type(4)));
typedef __bf16 bf16x8 __attribute__((ext_vector_type(8)));
typedef __bf16 bf16x4 __attribute__((ext_vector_type(4)));

// ---------------- workspace layout (bf16 element offsets) ----------------
// W' [t*8+g][h=128][k=640], k-order = [U | Wt0 | Wt1 | Wt2 | Ws]
#define WP_OFF   0u
#define HB_OFF   32112640u           // h  bf16 [B,T,N,H]
#define ACT_ELEMS 6422528u
#define PB_OFF   38535168u           // p  bf16
#define GB_OFF   44957696u           // g_t bf16 [B,T,H]
#define GT_ELEMS 100352u
#define ZP_OFF   45058048u           // 2048 bf16 zeros (pad source page)
#define ZB_OFF   45060096u           // f32 zb[b,t,g,h] = Zt.g_t + b  (802816 f32)
#define HM_OFF   46665728u           // f32 hm[b,t,h]   (100352 f32)
#define DTSG_OFF 46866432u           // f32 dtsg[m][b,t,h], m=0..2 (301056 f32)
#define W0P_OFF  47468544u           // bf16 Wg0^T [t][h][k] (802816)
// total = 48271360 bf16 units = 96.5 MB

#define OUT_H    0
#define OUT_CH   6422528
#define OUT_G    12845056
#define OUT_CG   12945408

#define KPAD 136
#define LDS1_BYTES 49152             // 3 slots x (A 8KB + B 8KB) -> 3 blocks/CU
#define LDS2_BYTES 73728             // A2 34816 + Wb 34816 + hm2 1024 + red 2048

#define NB_ACTS 12644
#define NB_ZB   392                  // 49*8
#define NB_W    1960                 // 392*5
#define NB_DTSG 147                  // 49*3
#define NB_W0   49

__device__ __forceinline__ float sigf(float x) {
    return 1.0f / (1.0f + exp2f(-1.442695041f * x));
}
__device__ __forceinline__ float tanhf_fast(float x) {
    x = fminf(fmaxf(x, -20.f), 20.f);
    float e = exp2f(2.885390082f * x);
    return (e - 1.f) / (e + 1.f);
}
__device__ __forceinline__ void gload16(const void* g, void* l) {
    __builtin_amdgcn_global_load_lds((const __attribute__((address_space(1))) void*)g,
                                     (__attribute__((address_space(3))) void*)l, 16, 0, 0);
}

// ---------------------------------------------------------------------------
// prep (merged): acts casts | zb | W' transpose | dtsg (g_t.Zg+bg) | Wg0^T.
// ---------------------------------------------------------------------------
__global__ __launch_bounds__(256) void prep_kernel(
    const float* __restrict__ h, const float* __restrict__ p,
    const float* __restrict__ g, const float* __restrict__ Zt,
    const float* __restrict__ bias, const float* __restrict__ U,
    const float* __restrict__ Wt, const float* __restrict__ Ws,
    const float* __restrict__ Zg, const float* __restrict__ bg,
    const float* __restrict__ Wg, __bf16* __restrict__ ws)
{
    __shared__ float gl[16][128];
    const int bid = blockIdx.x;
    const int tid = threadIdx.x;

    if (bid < NB_ACTS) {
        unsigned i = bid * 256u + tid;
        const unsigned HU = ACT_ELEMS / 4u, GU = GT_ELEMS / 4u;
        const float* src;
        unsigned dst;
        if (i < HU)              { src = h + (size_t)i * 4;            dst = HB_OFF + i * 4; }
        else if (i < 2u*HU)      { unsigned j = i - HU;    src = p + (size_t)j * 4; dst = PB_OFF + j * 4; }
        else if (i < 2u*HU + GU) { unsigned j = i - 2u*HU; src = g + (size_t)j * 4; dst = GB_OFF + j * 4; }
        else if (i < 2u*HU + GU + 512u) {
            unsigned j = i - 2u*HU - GU;
            bf16x4 z = {};
            *(bf16x4*)(ws + ZP_OFF + j * 4) = z;
            return;
        } else return;
        f32x4 v = *(const f32x4*)src;
        bf16x4 w;
        w[0] = (__bf16)v[0]; w[1] = (__bf16)v[1]; w[2] = (__bf16)v[2]; w[3] = (__bf16)v[3];
        *(bf16x4*)(ws + dst) = w;
        return;
    }

    if (bid < NB_ACTS + NB_ZB) {
        // ---- zb: block = (t, gate); g_t staged in LDS first
        int zid = bid - NB_ACTS;
        int t = zid >> 3, gg = zid & 7;
#pragma unroll
        for (int j = 0; j < 8; ++j) {
            int idx = j * 256 + tid;
            int b = idx >> 7, k = idx & 127;
            gl[b][k] = g[((b * TD + t) << 7) + k];
        }
        __syncthreads();
        int h_ = tid & 127, bh = tid >> 7;
        float* zbf = (float*)(ws + ZB_OFF);
        float s[8];
        float bv = bias[(gg * TD + t) * HD + h_];
#pragma unroll
        for (int b8 = 0; b8 < 8; ++b8) s[b8] = bv;
        const float* Zrow = Zt + ((size_t)(gg * TD + t) << 14) + h_;
#pragma unroll 4
        for (int k = 0; k < 128; ++k) {
            float zv = Zrow[k << 7];
#pragma unroll
            for (int b8 = 0; b8 < 8; ++b8)
                s[b8] += gl[bh * 8 + b8][k] * zv;
        }
#pragma unroll
        for (int b8 = 0; b8 < 8; ++b8) {
            int bt = (bh * 8 + b8) * TD + t;
            zbf[(bt * 8 + gg) * HD + h_] = s[b8];
        }
        return;
    }

    if (bid < NB_ACTS + NB_ZB + NB_W) {
        // ---- prep_w: register transpose, no LDS
        int wb = bid - NB_ACTS - NB_ZB;
        int tg = wb / 5, kc = wb % 5;
        int t = tg >> 3, gg = tg & 7;
        int gt = gg * TD + t;
        const float* S;
        int kloc0;
        if (kc == 0)      { S = U  + ((size_t)gt << 14); kloc0 = 0; }
        else if (kc <= 3) { S = Wt + (size_t)gt * 49152; kloc0 = (kc - 1) * 128; }
        else              { S = Ws + ((size_t)gt << 14); kloc0 = 0; }
        __bf16* wrow = ws + WP_OFF + (size_t)tg * 81920 + kc * 128;
#pragma unroll
        for (int u = 0; u < 8; ++u) {
            int gid = u * 256 + tid;
            int hh = gid >> 4, kq = gid & 15;
            const float* s = S + (size_t)(kloc0 + kq * 8) * 128 + hh;
            bf16x8 w;
#pragma unroll
            for (int j = 0; j < 8; ++j) w[j] = (__bf16)s[j * 128];
            *(bf16x8*)(wrow + (size_t)hh * 640 + kq * 8) = w;
        }
        return;
    }

    if (bid < NB_ACTS + NB_ZB + NB_W + NB_DTSG) {
        // ---- dtsg[m] = g_t . Zg[m] + bg[m]  (f32)
        int zid = bid - NB_ACTS - NB_ZB - NB_W;
        int t = zid / 3, m = zid % 3;
#pragma unroll
        for (int j = 0; j < 8; ++j) {
            int idx = j * 256 + tid;
            int b = idx >> 7, k = idx & 127;
            gl[b][k] = g[((b * TD + t) << 7) + k];
        }
        __syncthreads();
        int h_ = tid & 127, bh = tid >> 7;
        float* dtf = (float*)(ws + DTSG_OFF);
        float s[8];
        float bv = bg[(m * TD + t) * HD + h_];
#pragma unroll
        for (int b8 = 0; b8 < 8; ++b8) s[b8] = bv;
        const float* Zrow = Zg + ((size_t)(m * TD + t) << 14) + h_;
#pragma unroll 4
        for (int k = 0; k < 128; ++k) {
            float zv = Zrow[k << 7];
#pragma unroll
            for (int b8 = 0; b8 < 8; ++b8)
                s[b8] += gl[bh * 8 + b8][k] * zv;
        }
#pragma unroll
        for (int b8 = 0; b8 < 8; ++b8) {
            int bt = (bh * 8 + b8) * TD + t;
            dtf[(m * BD * TD + bt) * HD + h_] = s[b8];
        }
        return;
    }

    // ---- Wg0^T bf16: W0P[t][c][k] = Wg[0][t][k][c]
    {
        int t = bid - NB_ACTS - NB_ZB - NB_W - NB_DTSG;
        const float* S = Wg + ((size_t)t << 14);
        __bf16* dst0 = ws + W0P_OFF + (size_t)t * 16384;
#pragma unroll
        for (int u = 0; u < 8; ++u) {
            int gid = u * 256 + tid;
            int hh = gid >> 4, kq = gid & 15;
            const float* s = S + (size_t)(kq * 8) * 128 + hh;
            bf16x8 w;
#pragma unroll
            for (int j = 0; j < 8; ++j) w[j] = (__bf16)s[j * 128];
            *(bf16x8*)(dst0 + (size_t)hh * 128 + kq * 8) = w;
        }
    }
}

// ---------------------------------------------------------------------------
// Phase 1: 128x128 tile, BK=32, K=640 (20 steps), 3 LDS slots (48KB -> 3
// blocks/CU), depth-2 prefetch, counted vmcnt(4) + raw barrier. 4 waves,
// wave = 32 rows x all 8 gates (in-register gate epilogue, bias=zb).
// Epilogue also emits hm[b,t,hcol] = sum_n h_new / 64 (exact, block-local).
// ---------------------------------------------------------------------------
__global__ __launch_bounds__(256, 3) void phase1_kernel(
    const __bf16* __restrict__ ws,
    const float* __restrict__ c_h, const float* __restrict__ c_g_t,
    float* __restrict__ hmf, float* __restrict__ out)
{
    extern __shared__ __bf16 smem[];   // A slots: elems [0,12288); B: [12288,24576)
    const __bf16* hb = ws + HB_OFF;
    const __bf16* pb = ws + PB_OFF;
    const __bf16* wp = ws + WP_OFF;
    const __bf16* zp = ws + ZP_OFF;
    const float*  zb = (const float*)(ws + ZB_OFF);

    int bid = blockIdx.x;
    int swz = (bid & 7) * 392 + (bid >> 3);  // bijective, 3136 = 8*392
    int t     = swz >> 6;
    int rem   = swz & 63;
    int mtile = rem >> 3, ntile = rem & 7;

    int tid  = threadIdx.x;
    int wave = tid >> 6, lane = tid & 63;
    int lg = lane >> 4, l16 = lane & 15;

    const __bf16* pA[2][5];
    const __bf16* pB[2];
    int dstA[2], dstB[2];
#pragma unroll
    for (int it = 0; it < 2; ++it) {
        int chunk = it * 256 + tid;
        int row   = chunk >> 2;
        int k16   = chunk & 3;
        int ke    = (k16 ^ ((row >> 1) & 3)) * 8;
        int b_ = mtile * 2 + (row >> 6), n_ = row & 63, bt_ = b_ * TD + t;
        pA[it][0] = pb + ((bt_ * ND + n_) << 7) + ke;
        pA[it][1] = (t > 0)      ? hb + (((bt_ - 1) * ND + n_) << 7) + ke : zp + ke;
        pA[it][2] = hb + ((bt_ * ND + n_) << 7) + ke;
        pA[it][3] = (t < TD - 1) ? hb + (((bt_ + 1) * ND + n_) << 7) + ke : zp + ke;
        pA[it][4] = (n_ > 0)     ? hb + ((bt_ * ND + n_ - 1) << 7) + ke : zp + ke;
        int g_ = row >> 4, hc = row & 15;
        pB[it] = wp + (size_t)((t * 8 + g_) * 128 + ntile * 16 + hc) * 640 + ke;
        dstA[it] = chunk * 8;
        dstB[it] = 12288 + chunk * 8;
    }

    int rbA[2], rbB[8];
#pragma unroll
    for (int mi = 0; mi < 2; ++mi) {
        int row = wave * 32 + mi * 16 + l16;
        rbA[mi] = row * 64 + ((lg ^ ((row >> 1) & 3)) << 4);
    }
#pragma unroll
    for (int g = 0; g < 8; ++g) {
        int row = g * 16 + l16;
        rbB[g] = row * 64 + ((lg ^ ((row >> 1) & 3)) << 4);
    }

    f32x4 acc[2][8];
    const f32x4 vzero = {0.f, 0.f, 0.f, 0.f};
#pragma unroll
    for (int mi = 0; mi < 2; ++mi)
#pragma unroll
        for (int g = 0; g < 8; ++g) acc[mi][g] = vzero;

#define STAGE(KS) do {                                                          \
        const int sl = (KS) % 3;                                                \
        _Pragma("unroll")                                                       \
        for (int it = 0; it < 2; ++it) {                                        \
            gload16(pA[it][(KS) >> 2] + ((KS) & 3) * 32,                        \
                    smem + sl * 4096 + dstA[it]);                               \
            gload16(pB[it] + (KS) * 32,                                         \
                    smem + sl * 4096 + dstB[it]);                               \
        }                                                                       \
    } while (0)

    STAGE(0); STAGE(1);
    asm volatile("s_waitcnt vmcnt(4)" ::: "memory");
    __builtin_amdgcn_s_barrier();

#pragma unroll
    for (int ks = 0; ks < 20; ++ks) {
        if (ks + 2 < 20) STAGE(ks + 2);
        const char* Ab = (const char*)smem + (ks % 3) * 8192;
        const char* Bb = (const char*)smem + 24576 + (ks % 3) * 8192;
        bf16x8 af[2], bfr[8];
        af[0] = *(const bf16x8*)(Ab + rbA[0]);
        af[1] = *(const bf16x8*)(Ab + rbA[1]);
#pragma unroll
        for (int g = 0; g < 8; ++g)
            bfr[g] = *(const bf16x8*)(Bb + rbB[g]);
#pragma unroll
        for (int g = 0; g < 8; ++g) {
            acc[0][g] = __builtin_amdgcn_mfma_f32_16x16x32_bf16(af[0], bfr[g], acc[0][g], 0, 0, 0);
            acc[1][g] = __builtin_amdgcn_mfma_f32_16x16x32_bf16(af[1], bfr[g], acc[1][g], 0, 0, 0);
        }
        if (ks < 19) {
            if (ks + 2 < 20) asm volatile("s_waitcnt vmcnt(4)" ::: "memory");
            else             asm volatile("s_waitcnt vmcnt(0)" ::: "memory");
            __builtin_amdgcn_s_barrier();
        }
    }
#undef STAGE

    // ---- epilogue: gates + cell update; bias = zb; accumulate hm partial ----
    const int hcol = ntile * 16 + l16;
    float s_loc = 0.f;
#pragma unroll
    for (int mi = 0; mi < 2; ++mi) {
#pragma unroll
        for (int r = 0; r < 4; ++r) {
            int RG = mtile * 128 + wave * 32 + mi * 16 + lg * 4 + r;
            int b  = RG >> 6, nn = RG & 63;
            int bt = b * TD + t;
            int base = ((bt * ND + nn) << 7) + hcol;
            const float* zrow = zb + (bt * 8) * HD + hcol;
            float pre[8];
#pragma unroll
            for (int g = 0; g < 8; ++g) pre[g] = acc[mi][g][r] + zrow[g * HD];
            float i_  = sigf(pre[0]);
            float flt = sigf(pre[1]);
            float fft = sigf(pre[2]);
            float frt = sigf(pre[3]);
            float fs  = sigf(pre[4]);
            float gn  = sigf(pre[5]);
            float on  = sigf(pre[6]);
            float cn  = tanhf_fast(pre[7]);
            float ccur = c_h[base];
            float ctb  = (t > 0)      ? c_h[base - ND * HD] : 0.f;
            float cta  = (t < TD - 1) ? c_h[base + ND * HD] : 0.f;
            float csb  = (nn > 0)     ? c_h[base - HD]      : 0.f;
            float cg   = c_g_t[(bt << 7) + hcol];
            float cnew = i_ * cn + flt * ctb + fft * ccur + frt * cta + fs * csb + gn * cg;
            float hnew = on * tanhf_fast(cnew);
            out[OUT_H  + base] = hnew;
            out[OUT_CH + base] = cnew;
            s_loc += hnew;
        }
    }
    // hm reduce: sum over lg groups (32 rows/wave), then wave pairs -> 64 rows
    s_loc += __shfl_xor(s_loc, 16, 64);
    s_loc += __shfl_xor(s_loc, 32, 64);
    __syncthreads();                       // main loop done; reuse smem
    float* redf = (float*)smem;
    if (lane < 16) redf[wave * 16 + lane] = s_loc;
    __syncthreads();
    if (tid < 32) {
        int bsel = tid >> 4, c = tid & 15;
        float hv = (redf[(bsel * 2) * 16 + c] + redf[(bsel * 2 + 1) * 16 + c]) * (1.f / 64.f);
        hmf[((mtile * 2 + bsel) * TD + t) * HD + ntile * 16 + c] = hv;
    }
}

// ---------------------------------------------------------------------------
// Phase 2 v3: grid 49 t x 8 mtile (2 b's each), 392 blocks, 4 waves.
// f_gtf GEMM 128x128xK=128 (phase1-style MFMA), s3/s4 = hm.Wg1/2 scalar dots,
// dts0-2 precomputed in prep, hm precomputed in phase1.
// ---------------------------------------------------------------------------
__global__ __launch_bounds__(256, 2) void phase2_kernel(
    const __bf16* __restrict__ ws, const float* __restrict__ c_g_t,
    const float* __restrict__ Wg, float* __restrict__ out)
{
    extern __shared__ char sm2[];
    __bf16* A2  = (__bf16*)sm2;                       // [128][KPAD]
    __bf16* Wb  = (__bf16*)(sm2 + 34816);             // [128][KPAD]
    float*  hm2 = (float*)(sm2 + 69632);              // [2][128]
    float*  red = (float*)(sm2 + 70656);              // [4][128]

    int bid = blockIdx.x;
    int swz = (bid & 7) * 49 + (bid >> 3);            // bijective, 392 = 8*49
    int t = swz >> 3, mtile = swz & 7;
    int tid = threadIdx.x;
    int wv = tid >> 6, lane = tid & 63, lg = lane >> 4, l16 = lane & 15;

    const float* hn   = out + OUT_H;
    const float* chn  = out + OUT_CH;
    const float* hmf  = (const float*)(ws + HM_OFF);
    const float* dtf  = (const float*)(ws + DTSG_OFF);
    const __bf16* w0p = ws + W0P_OFF + (size_t)t * 16384;

    // ---- stage A2 (h_new f32 -> bf16), Wb (Wg0^T copy), hm2
#pragma unroll
    for (int j = 0; j < 16; ++j) {
        int fid = j * 256 + tid;                  // [0,4096): 128 rows x 32 f32x4
        int r = fid >> 5, k = (fid & 31) << 2;
        int b = mtile * 2 + (r >> 6), nn = r & 63, bt = b * TD + t;
        f32x4 v = *(const f32x4*)(hn + ((bt * ND + nn) << 7) + k);
        bf16x4 w;
        w[0] = (__bf16)v[0]; w[1] = (__bf16)v[1]; w[2] = (__bf16)v[2]; w[3] = (__bf16)v[3];
        *(bf16x4*)(A2 + r * KPAD + k) = w;
    }
#pragma unroll
    for (int j = 0; j < 8; ++j) {
        int idx = j * 256 + tid;                  // [0,2048): 128 rows x 16 bf16x8
        int hh = idx >> 4, kq = idx & 15;
        bf16x8 v = *(const bf16x8*)(w0p + hh * 128 + kq * 8);
        *(bf16x8*)(Wb + hh * KPAD + kq * 8) = v;
    }
    {
        int b4 = tid >> 7, c = tid & 127;
        hm2[b4 * 128 + c] = hmf[((mtile * 2 + b4) * TD + t) * HD + c];
    }
    __syncthreads();

    // ---- s3 = hm.Wg1[c], s4 = hm.Wg2[c]  (per thread: one (b4,c))
    float s3 = 0.f, s4 = 0.f;
    {
        int b4 = tid >> 7, c = tid & 127;
        const float* W1 = Wg + ((size_t)(TD + t) << 14) + c;
        const float* W2 = Wg + ((size_t)(2 * TD + t) << 14) + c;
#pragma unroll 4
        for (int k = 0; k < 128; ++k) {
            float hv = hm2[b4 * 128 + k];
            s3 += hv * W1[k << 7];
            s4 += hv * W2[k << 7];
        }
    }

    // ---- MFMA: 4 waves x 32 rows x 128 cols, K=128
    f32x4 acc[2][8];
    const f32x4 vzero = {0.f, 0.f, 0.f, 0.f};
#pragma unroll
    for (int mi = 0; mi < 2; ++mi)
#pragma unroll
        for (int g = 0; g < 8; ++g) acc[mi][g] = vzero;
#pragma unroll
    for (int ks = 0; ks < 4; ++ks) {
        int kb = ks * 32 + lg * 8;
        bf16x8 a0 = *(const bf16x8*)(A2 + (wv * 32 + l16) * KPAD + kb);
        bf16x8 a1 = *(const bf16x8*)(A2 + (wv * 32 + 16 + l16) * KPAD + kb);
#pragma unroll
        for (int g = 0; g < 8; ++g) {
            bf16x8 bfr = *(const bf16x8*)(Wb + (g * 16 + l16) * KPAD + kb);
            acc[0][g] = __builtin_amdgcn_mfma_f32_16x16x32_bf16(a0, bfr, acc[0][g], 0, 0, 0);
            acc[1][g] = __builtin_amdgcn_mfma_f32_16x16x32_bf16(a1, bfr, acc[1][g], 0, 0, 0);
        }
    }

    // ---- f_gtf epilogue: f = sig(acc + dts0), macc = sum_rows f*chn
    const int bw = mtile * 2 + (wv >> 1);             // b for this wave
    const int btw = bw * TD + t;
    const float* d0 = dtf + (0 * BD * TD + btw) * HD;
#pragma unroll
    for (int cf = 0; cf < 8; ++cf) {
        int col = cf * 16 + l16;
        float z = d0[col];
        float macc = 0.f;
#pragma unroll
        for (int mi = 0; mi < 2; ++mi) {
#pragma unroll
            for (int r = 0; r < 4; ++r) {
                int row = (wv & 1) * 32 + mi * 16 + lg * 4 + r;   // n within b
                float f  = sigf(acc[mi][cf][r] + z);
                float cv = chn[((btw * ND + row) << 7) + col];
                macc += f * cv;
            }
        }
        macc += __shfl_xor(macc, 16, 64);
        macc += __shfl_xor(macc, 32, 64);
        if (lane < 16) red[wv * 128 + col] = macc;
    }
    __syncthreads();
    {
        int b4 = tid >> 7, c = tid & 127;
        int bt = (mtile * 2 + b4) * TD + t;
        float Mn  = (red[(b4 * 2) * 128 + c] + red[(b4 * 2 + 1) * 128 + c]) * (1.f / 64.f);
        float g_g = sigf(s3 + dtf[(1 * BD * TD + bt) * HD + c]);
        float o_g = sigf(s4 + dtf[(2 * BD * TD + bt) * HD + c]);
        float cgt = c_g_t[(bt << 7) + c];
        float cgn = Mn + g_g * cgt;
        out[OUT_G  + (bt << 7) + c] = tanhf_fast(cgn) * o_g;
        out[OUT_CG + (bt << 7) + c] = cgn;
    }
}

extern "C" void kernel_launch(void* const* d_in, const int* in_sizes, int n_in,
                              void* d_out, int out_size, void* d_ws, size_t ws_size,
                              hipStream_t stream) {
    const float* h     = (const float*)d_in[0];
    const float* c_h   = (const float*)d_in[1];
    const float* p     = (const float*)d_in[2];
    const float* g_t   = (const float*)d_in[3];
    const float* c_g_t = (const float*)d_in[4];
    const float* U     = (const float*)d_in[5];
    const float* Wt    = (const float*)d_in[6];
    const float* Ws    = (const float*)d_in[7];
    const float* Zt    = (const float*)d_in[8];
    const float* b     = (const float*)d_in[9];
    const float* Wg    = (const float*)d_in[10];
    const float* Zg    = (const float*)d_in[11];
    const float* bg    = (const float*)d_in[12];
    float* out = (float*)d_out;
    __bf16* ws = (__bf16*)d_ws;

    prep_kernel<<<NB_ACTS + NB_ZB + NB_W + NB_DTSG + NB_W0, 256, 0, stream>>>(
        h, p, g_t, Zt, b, U, Wt, Ws, Zg, bg, Wg, ws);

    (void)hipFuncSetAttribute(reinterpret_cast<const void*>(phase1_kernel),
                              hipFuncAttributeMaxDynamicSharedMemorySize, LDS1_BYTES);
    (void)hipFuncSetAttribute(reinterpret_cast<const void*>(phase2_kernel),
                              hipFuncAttributeMaxDynamicSharedMemorySize, LDS2_BYTES);
    phase1_kernel<<<TD * 64, 256, LDS1_BYTES, stream>>>(
        ws, c_h, c_g_t, (float*)(ws + HM_OFF), out);
    phase2_kernel<<<TD * 8, 256, LDS2_BYTES, stream>>>(ws, c_g_t, Wg, out);
}

// Round 14
// 207.329 us; speedup vs baseline: 1.8156x; 1.1878x over previous
//
#include <hip/hip_runtime.h>
#include <hip/hip_bf16.h>

#define TD 49
#define BD 16
#define ND 64
#define HD 128

typedef float  f32x4  __attribute__((ext_vector_type(4)));
typedef __bf16 bf16x8 __attribute__((ext_vector_type(8)));
typedef __bf16 bf16x4 __attribute__((ext_vector_type(4)));

// ---------------- workspace layout (bf16 element offsets) ----------------
// W' [t*8+g][h=128][k=640], k-order = [U | Wt0 | Wt1 | Wt2 | Ws]
#define WP_OFF   0u
#define HB_OFF   32112640u           // h  bf16 [B,T,N,H]
#define ACT_ELEMS 6422528u
#define PB_OFF   38535168u           // p  bf16
#define GB_OFF   44957696u           // g_t bf16 [B,T,H]
#define GT_ELEMS 100352u
#define ZP_OFF   45058048u           // 2048 bf16 zeros (pad source page)
#define ZB_OFF   45060096u           // f32 zb[b,t,g,h] = Zt.g_t + b  (802816 f32)
#define HM_OFF   46665728u           // f32 hm[b,t,h]   (100352 f32)
#define DTSG_OFF 46866432u           // f32 dtsg[m][b,t,h], m=0..2 (301056 f32)
#define W0P_OFF  47468544u           // bf16 Wg0^T [t][h][k] (802816)
// total = 48271360 bf16 units = 96.5 MB

#define OUT_H    0
#define OUT_CH   6422528
#define OUT_G    12845056
#define OUT_CG   12945408

#define KPAD 136
#define LDS1_BYTES 49152             // 3 slots x (A 8KB + B 8KB) -> 3 blocks/CU
#define LDS2_BYTES 73728             // A2 34816 + Wb 34816 + hm2 1024 + red 2048

#define NB_ACTS 12644
#define NB_ZB   392                  // 49*8
#define NB_W    3920                 // 49*8*10 (64-k chunks, LDS transpose)
#define NB_DTSG 147                  // 49*3
#define NB_W0   49

__device__ __forceinline__ float sigf(float x) {
    return 1.0f / (1.0f + exp2f(-1.442695041f * x));
}
__device__ __forceinline__ float tanhf_fast(float x) {
    x = fminf(fmaxf(x, -20.f), 20.f);
    float e = exp2f(2.885390082f * x);
    return (e - 1.f) / (e + 1.f);
}
__device__ __forceinline__ void gload16(const void* g, void* l) {
    __builtin_amdgcn_global_load_lds((const __attribute__((address_space(1))) void*)g,
                                     (__attribute__((address_space(3))) void*)l, 16, 0, 0);
}

// ---------------------------------------------------------------------------
// prep (merged): acts casts | zb | W' transpose (LDS tile, R3-proven) |
// dtsg (g_t.Zg+bg) | Wg0^T.  gl/tile share one LDS buffer (16.9KB).
// ---------------------------------------------------------------------------
__global__ __launch_bounds__(256) void prep_kernel(
    const float* __restrict__ h, const float* __restrict__ p,
    const float* __restrict__ g, const float* __restrict__ Zt,
    const float* __restrict__ bias, const float* __restrict__ U,
    const float* __restrict__ Wt, const float* __restrict__ Ws,
    const float* __restrict__ Zg, const float* __restrict__ bg,
    const float* __restrict__ Wg, __bf16* __restrict__ ws)
{
    __shared__ char shbuf[64 * 132 * 2];             // 16.9KB, shared by gl/tile
    float  (*gl)[128] = (float(*)[128])shbuf;        // [16][128] f32 (8KB)
    __bf16* tile      = (__bf16*)shbuf;              // [64][132] bf16
    const int bid = blockIdx.x;
    const int tid = threadIdx.x;

    if (bid < NB_ACTS) {
        unsigned i = bid * 256u + tid;
        const unsigned HU = ACT_ELEMS / 4u, GU = GT_ELEMS / 4u;
        const float* src;
        unsigned dst;
        if (i < HU)              { src = h + (size_t)i * 4;            dst = HB_OFF + i * 4; }
        else if (i < 2u*HU)      { unsigned j = i - HU;    src = p + (size_t)j * 4; dst = PB_OFF + j * 4; }
        else if (i < 2u*HU + GU) { unsigned j = i - 2u*HU; src = g + (size_t)j * 4; dst = GB_OFF + j * 4; }
        else if (i < 2u*HU + GU + 512u) {
            unsigned j = i - 2u*HU - GU;
            bf16x4 z = {};
            *(bf16x4*)(ws + ZP_OFF + j * 4) = z;
            return;
        } else return;
        f32x4 v = *(const f32x4*)src;
        bf16x4 w;
        w[0] = (__bf16)v[0]; w[1] = (__bf16)v[1]; w[2] = (__bf16)v[2]; w[3] = (__bf16)v[3];
        *(bf16x4*)(ws + dst) = w;
        return;
    }

    if (bid < NB_ACTS + NB_ZB) {
        // ---- zb: block = (t, gate); g_t staged in LDS first
        int zid = bid - NB_ACTS;
        int t = zid >> 3, gg = zid & 7;
#pragma unroll
        for (int j = 0; j < 8; ++j) {
            int idx = j * 256 + tid;
            int b = idx >> 7, k = idx & 127;
            gl[b][k] = g[((b * TD + t) << 7) + k];
        }
        __syncthreads();
        int h_ = tid & 127, bh = tid >> 7;
        float* zbf = (float*)(ws + ZB_OFF);
        float s[8];
        float bv = bias[(gg * TD + t) * HD + h_];
#pragma unroll
        for (int b8 = 0; b8 < 8; ++b8) s[b8] = bv;
        const float* Zrow = Zt + ((size_t)(gg * TD + t) << 14) + h_;
#pragma unroll 4
        for (int k = 0; k < 128; ++k) {
            float zv = Zrow[k << 7];
#pragma unroll
            for (int b8 = 0; b8 < 8; ++b8)
                s[b8] += gl[bh * 8 + b8][k] * zv;
        }
#pragma unroll
        for (int b8 = 0; b8 < 8; ++b8) {
            int bt = (bh * 8 + b8) * TD + t;
            zbf[(bt * 8 + gg) * HD + h_] = s[b8];
        }
        return;
    }

    if (bid < NB_ACTS + NB_ZB + NB_W) {
        // ---- prep_w (LDS transpose, R3-proven): block = (tg, 64-k chunk)
        int wb = bid - NB_ACTS - NB_ZB;
        int tg = wb / 10, c = wb % 10;
        int t  = tg >> 3, gg = tg & 7;
        int gt = gg * TD + t;
        int k0 = c * 64;
#pragma unroll
        for (int u = 0; u < 8; ++u) {
            int unit = u * 256 + tid;        // [0,2048): 64 kk x 32 f32x4
            int kk = unit >> 5;
            int h4 = (unit & 31) << 2;
            int k  = k0 + kk;
            const float* src;
            if (k < 128)      src = U  + ((size_t)(gt * 128 + k)       << 7);
            else if (k < 512) src = Wt + ((size_t)(gt * 384 + (k-128)) << 7);
            else              src = Ws + ((size_t)(gt * 128 + (k-512)) << 7);
            f32x4 v = *(const f32x4*)(src + h4);
            bf16x4 w;
            w[0] = (__bf16)v[0]; w[1] = (__bf16)v[1]; w[2] = (__bf16)v[2]; w[3] = (__bf16)v[3];
            *(bf16x4*)(tile + kk * 132 + h4) = w;
        }
        __syncthreads();
#pragma unroll
        for (int u = 0; u < 2; ++u) {
            int unit = u * 256 + tid;        // [0,512): 128 hh x 4 kg
            int hh = unit >> 2;
            int kg = unit & 3;
            bf16x8 v0, v1;
#pragma unroll
            for (int j = 0; j < 8; ++j) v0[j] = tile[(kg * 16 + j) * 132 + hh];
#pragma unroll
            for (int j = 0; j < 8; ++j) v1[j] = tile[(kg * 16 + 8 + j) * 132 + hh];
            __bf16* dst = ws + WP_OFF + (size_t)tg * 81920 + (size_t)hh * 640 + k0 + kg * 16;
            *(bf16x8*)dst       = v0;
            *(bf16x8*)(dst + 8) = v1;
        }
        return;
    }

    if (bid < NB_ACTS + NB_ZB + NB_W + NB_DTSG) {
        // ---- dtsg[m] = g_t . Zg[m] + bg[m]  (f32)
        int zid = bid - NB_ACTS - NB_ZB - NB_W;
        int t = zid / 3, m = zid % 3;
#pragma unroll
        for (int j = 0; j < 8; ++j) {
            int idx = j * 256 + tid;
            int b = idx >> 7, k = idx & 127;
            gl[b][k] = g[((b * TD + t) << 7) + k];
        }
        __syncthreads();
        int h_ = tid & 127, bh = tid >> 7;
        float* dtf = (float*)(ws + DTSG_OFF);
        float s[8];
        float bv = bg[(m * TD + t) * HD + h_];
#pragma unroll
        for (int b8 = 0; b8 < 8; ++b8) s[b8] = bv;
        const float* Zrow = Zg + ((size_t)(m * TD + t) << 14) + h_;
#pragma unroll 4
        for (int k = 0; k < 128; ++k) {
            float zv = Zrow[k << 7];
#pragma unroll
            for (int b8 = 0; b8 < 8; ++b8)
                s[b8] += gl[bh * 8 + b8][k] * zv;
        }
#pragma unroll
        for (int b8 = 0; b8 < 8; ++b8) {
            int bt = (bh * 8 + b8) * TD + t;
            dtf[(m * BD * TD + bt) * HD + h_] = s[b8];
        }
        return;
    }

    // ---- Wg0^T bf16 via LDS tile (two 64-k chunks in sequence)
    {
        int t = bid - NB_ACTS - NB_ZB - NB_W - NB_DTSG;
        const float* S = Wg + ((size_t)t << 14);
        __bf16* dst0 = ws + W0P_OFF + (size_t)t * 16384;
#pragma unroll
        for (int half = 0; half < 2; ++half) {
            __syncthreads();
            int k0 = half * 64;
#pragma unroll
            for (int u = 0; u < 8; ++u) {
                int unit = u * 256 + tid;
                int kk = unit >> 5;
                int h4 = (unit & 31) << 2;
                f32x4 v = *(const f32x4*)(S + ((size_t)(k0 + kk) << 7) + h4);
                bf16x4 w;
                w[0] = (__bf16)v[0]; w[1] = (__bf16)v[1]; w[2] = (__bf16)v[2]; w[3] = (__bf16)v[3];
                *(bf16x4*)(tile + kk * 132 + h4) = w;
            }
            __syncthreads();
#pragma unroll
            for (int u = 0; u < 2; ++u) {
                int unit = u * 256 + tid;
                int hh = unit >> 2;
                int kg = unit & 3;
                bf16x8 v0, v1;
#pragma unroll
                for (int j = 0; j < 8; ++j) v0[j] = tile[(kg * 16 + j) * 132 + hh];
#pragma unroll
                for (int j = 0; j < 8; ++j) v1[j] = tile[(kg * 16 + 8 + j) * 132 + hh];
                __bf16* dst = dst0 + (size_t)hh * 128 + k0 + kg * 16;
                *(bf16x8*)dst       = v0;
                *(bf16x8*)(dst + 8) = v1;
            }
        }
    }
}

// ---------------------------------------------------------------------------
// Phase 1: 128x128 tile, BK=32, K=640 (20 steps), 3 LDS slots (48KB -> 3
// blocks/CU), depth-2 prefetch, counted vmcnt(4) + raw barrier. 4 waves,
// wave = 32 rows x all 8 gates (in-register gate epilogue, bias=zb).
// Epilogue also emits hm[b,t,hcol] = sum_n h_new / 64 (exact, block-local).
// ---------------------------------------------------------------------------
__global__ __launch_bounds__(256, 3) void phase1_kernel(
    const __bf16* __restrict__ ws,
    const float* __restrict__ c_h, const float* __restrict__ c_g_t,
    float* __restrict__ hmf, float* __restrict__ out)
{
    extern __shared__ __bf16 smem[];   // A slots: elems [0,12288); B: [12288,24576)
    const __bf16* hb = ws + HB_OFF;
    const __bf16* pb = ws + PB_OFF;
    const __bf16* wp = ws + WP_OFF;
    const __bf16* zp = ws + ZP_OFF;
    const float*  zb = (const float*)(ws + ZB_OFF);

    int bid = blockIdx.x;
    int swz = (bid & 7) * 392 + (bid >> 3);  // bijective, 3136 = 8*392
    int t     = swz >> 6;
    int rem   = swz & 63;
    int mtile = rem >> 3, ntile = rem & 7;

    int tid  = threadIdx.x;
    int wave = tid >> 6, lane = tid & 63;
    int lg = lane >> 4, l16 = lane & 15;

    const __bf16* pA[2][5];
    const __bf16* pB[2];
    int dstA[2], dstB[2];
#pragma unroll
    for (int it = 0; it < 2; ++it) {
        int chunk = it * 256 + tid;
        int row   = chunk >> 2;
        int k16   = chunk & 3;
        int ke    = (k16 ^ ((row >> 1) & 3)) * 8;
        int b_ = mtile * 2 + (row >> 6), n_ = row & 63, bt_ = b_ * TD + t;
        pA[it][0] = pb + ((bt_ * ND + n_) << 7) + ke;
        pA[it][1] = (t > 0)      ? hb + (((bt_ - 1) * ND + n_) << 7) + ke : zp + ke;
        pA[it][2] = hb + ((bt_ * ND + n_) << 7) + ke;
        pA[it][3] = (t < TD - 1) ? hb + (((bt_ + 1) * ND + n_) << 7) + ke : zp + ke;
        pA[it][4] = (n_ > 0)     ? hb + ((bt_ * ND + n_ - 1) << 7) + ke : zp + ke;
        int g_ = row >> 4, hc = row & 15;
        pB[it] = wp + (size_t)((t * 8 + g_) * 128 + ntile * 16 + hc) * 640 + ke;
        dstA[it] = chunk * 8;
        dstB[it] = 12288 + chunk * 8;
    }

    int rbA[2], rbB[8];
#pragma unroll
    for (int mi = 0; mi < 2; ++mi) {
        int row = wave * 32 + mi * 16 + l16;
        rbA[mi] = row * 64 + ((lg ^ ((row >> 1) & 3)) << 4);
    }
#pragma unroll
    for (int g = 0; g < 8; ++g) {
        int row = g * 16 + l16;
        rbB[g] = row * 64 + ((lg ^ ((row >> 1) & 3)) << 4);
    }

    f32x4 acc[2][8];
    const f32x4 vzero = {0.f, 0.f, 0.f, 0.f};
#pragma unroll
    for (int mi = 0; mi < 2; ++mi)
#pragma unroll
        for (int g = 0; g < 8; ++g) acc[mi][g] = vzero;

#define STAGE(KS) do {                                                          \
        const int sl = (KS) % 3;                                                \
        _Pragma("unroll")                                                       \
        for (int it = 0; it < 2; ++it) {                                        \
            gload16(pA[it][(KS) >> 2] + ((KS) & 3) * 32,                        \
                    smem + sl * 4096 + dstA[it]);                               \
            gload16(pB[it] + (KS) * 32,                                         \
                    smem + sl * 4096 + dstB[it]);                               \
        }                                                                       \
    } while (0)

    STAGE(0); STAGE(1);
    asm volatile("s_waitcnt vmcnt(4)" ::: "memory");
    __builtin_amdgcn_s_barrier();

#pragma unroll
    for (int ks = 0; ks < 20; ++ks) {
        if (ks + 2 < 20) STAGE(ks + 2);
        const char* Ab = (const char*)smem + (ks % 3) * 8192;
        const char* Bb = (const char*)smem + 24576 + (ks % 3) * 8192;
        bf16x8 af[2], bfr[8];
        af[0] = *(const bf16x8*)(Ab + rbA[0]);
        af[1] = *(const bf16x8*)(Ab + rbA[1]);
#pragma unroll
        for (int g = 0; g < 8; ++g)
            bfr[g] = *(const bf16x8*)(Bb + rbB[g]);
#pragma unroll
        for (int g = 0; g < 8; ++g) {
            acc[0][g] = __builtin_amdgcn_mfma_f32_16x16x32_bf16(af[0], bfr[g], acc[0][g], 0, 0, 0);
            acc[1][g] = __builtin_amdgcn_mfma_f32_16x16x32_bf16(af[1], bfr[g], acc[1][g], 0, 0, 0);
        }
        if (ks < 19) {
            if (ks + 2 < 20) asm volatile("s_waitcnt vmcnt(4)" ::: "memory");
            else             asm volatile("s_waitcnt vmcnt(0)" ::: "memory");
            __builtin_amdgcn_s_barrier();
        }
    }
#undef STAGE

    // ---- epilogue: gates + cell update; bias = zb; accumulate hm partial ----
    const int hcol = ntile * 16 + l16;
    float s_loc = 0.f;
#pragma unroll
    for (int mi = 0; mi < 2; ++mi) {
#pragma unroll
        for (int r = 0; r < 4; ++r) {
            int RG = mtile * 128 + wave * 32 + mi * 16 + lg * 4 + r;
            int b  = RG >> 6, nn = RG & 63;
            int bt = b * TD + t;
            int base = ((bt * ND + nn) << 7) + hcol;
            const float* zrow = zb + (bt * 8) * HD + hcol;
            float pre[8];
#pragma unroll
            for (int g = 0; g < 8; ++g) pre[g] = acc[mi][g][r] + zrow[g * HD];
            float i_  = sigf(pre[0]);
            float flt = sigf(pre[1]);
            float fft = sigf(pre[2]);
            float frt = sigf(pre[3]);
            float fs  = sigf(pre[4]);
            float gn  = sigf(pre[5]);
            float on  = sigf(pre[6]);
            float cn  = tanhf_fast(pre[7]);
            float ccur = c_h[base];
            float ctb  = (t > 0)      ? c_h[base - ND * HD] : 0.f;
            float cta  = (t < TD - 1) ? c_h[base + ND * HD] : 0.f;
            float csb  = (nn > 0)     ? c_h[base - HD]      : 0.f;
            float cg   = c_g_t[(bt << 7) + hcol];
            float cnew = i_ * cn + flt * ctb + fft * ccur + frt * cta + fs * csb + gn * cg;
            float hnew = on * tanhf_fast(cnew);
            out[OUT_H  + base] = hnew;
            out[OUT_CH + base] = cnew;
            s_loc += hnew;
        }
    }
    // hm reduce: sum over lg groups (32 rows/wave), then wave pairs -> 64 rows
    s_loc += __shfl_xor(s_loc, 16, 64);
    s_loc += __shfl_xor(s_loc, 32, 64);
    __syncthreads();                       // main loop done; reuse smem
    float* redf = (float*)smem;
    if (lane < 16) redf[wave * 16 + lane] = s_loc;
    __syncthreads();
    if (tid < 32) {
        int bsel = tid >> 4, c = tid & 15;
        float hv = (redf[(bsel * 2) * 16 + c] + redf[(bsel * 2 + 1) * 16 + c]) * (1.f / 64.f);
        hmf[((mtile * 2 + bsel) * TD + t) * HD + ntile * 16 + c] = hv;
    }
}

// ---------------------------------------------------------------------------
// Phase 2 v3: grid 49 t x 8 mtile (2 b's each), 392 blocks, 4 waves.
// f_gtf GEMM 128x128xK=128 (phase1-style MFMA), s3/s4 = hm.Wg1/2 scalar dots,
// dts0-2 precomputed in prep, hm precomputed in phase1.
// ---------------------------------------------------------------------------
__global__ __launch_bounds__(256, 2) void phase2_kernel(
    const __bf16* __restrict__ ws, const float* __restrict__ c_g_t,
    const float* __restrict__ Wg, float* __restrict__ out)
{
    extern __shared__ char sm2[];
    __bf16* A2  = (__bf16*)sm2;                       // [128][KPAD]
    __bf16* Wb  = (__bf16*)(sm2 + 34816);             // [128][KPAD]
    float*  hm2 = (float*)(sm2 + 69632);              // [2][128]
    float*  red = (float*)(sm2 + 70656);              // [4][128]

    int bid = blockIdx.x;
    int swz = (bid & 7) * 49 + (bid >> 3);            // bijective, 392 = 8*49
    int t = swz >> 3, mtile = swz & 7;
    int tid = threadIdx.x;
    int wv = tid >> 6, lane = tid & 63, lg = lane >> 4, l16 = lane & 15;

    const float* hn   = out + OUT_H;
    const float* chn  = out + OUT_CH;
    const float* hmf  = (const float*)(ws + HM_OFF);
    const float* dtf  = (const float*)(ws + DTSG_OFF);
    const __bf16* w0p = ws + W0P_OFF + (size_t)t * 16384;

    // ---- stage A2 (h_new f32 -> bf16), Wb (Wg0^T copy), hm2
#pragma unroll
    for (int j = 0; j < 16; ++j) {
        int fid = j * 256 + tid;                  // [0,4096): 128 rows x 32 f32x4
        int r = fid >> 5, k = (fid & 31) << 2;
        int b = mtile * 2 + (r >> 6), nn = r & 63, bt = b * TD + t;
        f32x4 v = *(const f32x4*)(hn + ((bt * ND + nn) << 7) + k);
        bf16x4 w;
        w[0] = (__bf16)v[0]; w[1] = (__bf16)v[1]; w[2] = (__bf16)v[2]; w[3] = (__bf16)v[3];
        *(bf16x4*)(A2 + r * KPAD + k) = w;
    }
#pragma unroll
    for (int j = 0; j < 8; ++j) {
        int idx = j * 256 + tid;                  // [0,2048): 128 rows x 16 bf16x8
        int hh = idx >> 4, kq = idx & 15;
        bf16x8 v = *(const bf16x8*)(w0p + hh * 128 + kq * 8);
        *(bf16x8*)(Wb + hh * KPAD + kq * 8) = v;
    }
    {
        int b4 = tid >> 7, c = tid & 127;
        hm2[b4 * 128 + c] = hmf[((mtile * 2 + b4) * TD + t) * HD + c];
    }
    __syncthreads();

    // ---- s3 = hm.Wg1[c], s4 = hm.Wg2[c]  (per thread: one (b4,c))
    float s3 = 0.f, s4 = 0.f;
    {
        int b4 = tid >> 7, c = tid & 127;
        const float* W1 = Wg + ((size_t)(TD + t) << 14) + c;
        const float* W2 = Wg + ((size_t)(2 * TD + t) << 14) + c;
#pragma unroll 4
        for (int k = 0; k < 128; ++k) {
            float hv = hm2[b4 * 128 + k];
            s3 += hv * W1[k << 7];
            s4 += hv * W2[k << 7];
        }
    }

    // ---- MFMA: 4 waves x 32 rows x 128 cols, K=128
    f32x4 acc[2][8];
    const f32x4 vzero = {0.f, 0.f, 0.f, 0.f};
#pragma unroll
    for (int mi = 0; mi < 2; ++mi)
#pragma unroll
        for (int g = 0; g < 8; ++g) acc[mi][g] = vzero;
#pragma unroll
    for (int ks = 0; ks < 4; ++ks) {
        int kb = ks * 32 + lg * 8;
        bf16x8 a0 = *(const bf16x8*)(A2 + (wv * 32 + l16) * KPAD + kb);
        bf16x8 a1 = *(const bf16x8*)(A2 + (wv * 32 + 16 + l16) * KPAD + kb);
#pragma unroll
        for (int g = 0; g < 8; ++g) {
            bf16x8 bfr = *(const bf16x8*)(Wb + (g * 16 + l16) * KPAD + kb);
            acc[0][g] = __builtin_amdgcn_mfma_f32_16x16x32_bf16(a0, bfr, acc[0][g], 0, 0, 0);
            acc[1][g] = __builtin_amdgcn_mfma_f32_16x16x32_bf16(a1, bfr, acc[1][g], 0, 0, 0);
        }
    }

    // ---- f_gtf epilogue: f = sig(acc + dts0), macc = sum_rows f*chn
    const int bw = mtile * 2 + (wv >> 1);             // b for this wave
    const int btw = bw * TD + t;
    const float* d0 = dtf + (0 * BD * TD + btw) * HD;
#pragma unroll
    for (int cf = 0; cf < 8; ++cf) {
        int col = cf * 16 + l16;
        float z = d0[col];
        float macc = 0.f;
#pragma unroll
        for (int mi = 0; mi < 2; ++mi) {
#pragma unroll
            for (int r = 0; r < 4; ++r) {
                int row = (wv & 1) * 32 + mi * 16 + lg * 4 + r;   // n within b
                float f  = sigf(acc[mi][cf][r] + z);
                float cv = chn[((btw * ND + row) << 7) + col];
                macc += f * cv;
            }
        }
        macc += __shfl_xor(macc, 16, 64);
        macc += __shfl_xor(macc, 32, 64);
        if (lane < 16) red[wv * 128 + col] = macc;
    }
    __syncthreads();
    {
        int b4 = tid >> 7, c = tid & 127;
        int bt = (mtile * 2 + b4) * TD + t;
        float Mn  = (red[(b4 * 2) * 128 + c] + red[(b4 * 2 + 1) * 128 + c]) * (1.f / 64.f);
        float g_g = sigf(s3 + dtf[(1 * BD * TD + bt) * HD + c]);
        float o_g = sigf(s4 + dtf[(2 * BD * TD + bt) * HD + c]);
        float cgt = c_g_t[(bt << 7) + c];
        float cgn = Mn + g_g * cgt;
        out[OUT_G  + (bt << 7) + c] = tanhf_fast(cgn) * o_g;
        out[OUT_CG + (bt << 7) + c] = cgn;
    }
}

extern "C" void kernel_launch(void* const* d_in, const int* in_sizes, int n_in,
                              void* d_out, int out_size, void* d_ws, size_t ws_size,
                              hipStream_t stream) {
    const float* h     = (const float*)d_in[0];
    const float* c_h   = (const float*)d_in[1];
    const float* p     = (const float*)d_in[2];
    const float* g_t   = (const float*)d_in[3];
    const float* c_g_t = (const float*)d_in[4];
    const float* U     = (const float*)d_in[5];
    const float* Wt    = (const float*)d_in[6];
    const float* Ws    = (const float*)d_in[7];
    const float* Zt    = (const float*)d_in[8];
    const float* b     = (const float*)d_in[9];
    const float* Wg    = (const float*)d_in[10];
    const float* Zg    = (const float*)d_in[11];
    const float* bg    = (const float*)d_in[12];
    float* out = (float*)d_out;
    __bf16* ws = (__bf16*)d_ws;

    prep_kernel<<<NB_ACTS + NB_ZB + NB_W + NB_DTSG + NB_W0, 256, 0, stream>>>(
        h, p, g_t, Zt, b, U, Wt, Ws, Zg, bg, Wg, ws);

    (void)hipFuncSetAttribute(reinterpret_cast<const void*>(phase1_kernel),
                              hipFuncAttributeMaxDynamicSharedMemorySize, LDS1_BYTES);
    (void)hipFuncSetAttribute(reinterpret_cast<const void*>(phase2_kernel),
                              hipFuncAttributeMaxDynamicSharedMemorySize, LDS2_BYTES);
    phase1_kernel<<<TD * 64, 256, LDS1_BYTES, stream>>>(
        ws, c_h, c_g_t, (float*)(ws + HM_OFF), out);
    phase2_kernel<<<TD * 8, 256, LDS2_BYTES, stream>>>(ws, c_g_t, Wg, out);
}